// Round 11
// baseline (504.452 us; speedup 1.0000x reference)
//
#include <hip/hip_runtime.h>
#include <hip/hip_bf16.h>
#include <math.h>

#define NB 32
#define LSEQ 2048
#define DIN 64
#define NH 256
#define NN 32
#define NLAY 2
#define NCH 32
#define TCH 64    // LSEQ/NCH
#define NBC (NB*NCH)          // 1024 columns
#define LT 32                 // proj l-tile
#define ML1 350
#define ML2 400
#define MOUT 1024
#define LN_EPS 1e-5f

typedef short short8 __attribute__((ext_vector_type(8)));
typedef short short4v __attribute__((ext_vector_type(4)));
typedef float f32x4 __attribute__((ext_vector_type(4)));

__device__ __forceinline__ float bf2f(ushort u) {
    union { uint i; float f; } v; v.i = ((uint)u) << 16; return v.f;
}
__device__ __forceinline__ ushort f2bf(float f) {
    __hip_bfloat16 h = __float2bfloat16(f);
    return *reinterpret_cast<ushort*>(&h);
}

// ---------------- coefficient prep (E^64 for scan) ----------------
__global__ void s4w_coef(const float* __restrict__ log_dt,
                         const float* __restrict__ log_A_real, const float* __restrict__ A_imag,
                         float* __restrict__ pr_, float* __restrict__ pi_) {
    int idx = blockIdx.x * 256 + threadIdx.x;
    if (idx >= NLAY * NH * NN) return;
    int h = (idx / NN) % NH;
    int l = idx / (NN * NH);
    float dt = expf(log_dt[l * NH + h]);
    float ar = -expf(log_A_real[idx]);
    float ai = A_imag[idx];
    double dre = (double)(ar * dt), dim = (double)(ai * dt);
    double exT = exp(dre * (double)TCH);
    double ang = dim * (double)TCH;
    pr_[idx] = (float)(exT * cos(ang));
    pi_[idx] = (float)(exT * sin(ang));
}

// ---------------- matrix prep: Lmat (causal kernel), Wc (carry), Vmat (end-state) ----------------
__global__ void s4w_matprep(const float* __restrict__ log_dt,
                            const float* __restrict__ C_re, const float* __restrict__ C_im,
                            const float* __restrict__ log_A_real, const float* __restrict__ A_imag,
                            ushort* __restrict__ Lmat, ushort* __restrict__ Wc,
                            ushort* __restrict__ Vmat) {
    int lh = blockIdx.x;          // layer*NH + h
    int t = threadIdx.x;          // 0..63
    __shared__ float ksh[64];
    float dt = expf(log_dt[lh]);
    float kacc = 0.f;
    for (int n = 0; n < NN; n++) {
        int idx = lh * NN + n;
        float ar = -expf(log_A_real[idx]);
        float ai = A_imag[idx];
        float dre = ar * dt, dim = ai * dt;
        float e1 = expf(dre);
        float er1 = e1 * cosf(dim), ei1 = e1 * sinf(dim);
        float den = ar * ar + ai * ai;
        float qr = ((er1 - 1.f) * ar + ei1 * ai) / den;
        float qi = (ei1 * ar - (er1 - 1.f) * ai) / den;
        float cr = C_re[idx], ci = C_im[idx];
        float ctr = 2.f * (cr * qr - ci * qi);
        float cti = 2.f * (cr * qi + ci * qr);
        float ed = expf(dre * (float)t);
        float angd = dim * (float)t;
        float erd = ed * cosf(angd), eid = ed * sinf(angd);
        kacc += ctr * erd - cti * eid;
        float ew = expf(dre * (float)(t + 1));
        float angw = dim * (float)(t + 1);
        float ewr = ew * cosf(angw), ewi = ew * sinf(angw);
        float wr = ctr * ewr - cti * ewi;
        float wi = ctr * ewi + cti * ewr;
        Wc[(size_t)lh * 4096 + t * 64 + 2 * n]     = f2bf(wr);
        Wc[(size_t)lh * 4096 + t * 64 + 2 * n + 1] = f2bf(-wi);
        float ev = expf(dre * (float)(63 - t));
        float angv = dim * (float)(63 - t);
        Vmat[(size_t)lh * 4096 + (2 * n) * 64 + t]     = f2bf(ev * cosf(angv));
        Vmat[(size_t)lh * 4096 + (2 * n + 1) * 64 + t] = f2bf(ev * sinf(angv));
    }
    ksh[t] = kacc;
    __syncthreads();
    for (int j = 0; j < 64; j++)
        Lmat[(size_t)lh * 4096 + t * 64 + j] = (j <= t) ? f2bf(ksh[t - j]) : (ushort)0;
}

// ---------------- weight prep: out_w -> bf16 ----------------
__global__ void s4w_wprep(const float* __restrict__ ow, ushort* __restrict__ wbf) {
    int idx = blockIdx.x * 256 + threadIdx.x;
    wbf[idx] = f2bf(ow[idx]);
}

// ---------------- encoder ----------------
__global__ void __launch_bounds__(256, 2)
s4w_enc(const float* __restrict__ x, const float* __restrict__ w,
        const float* __restrict__ bias, float* __restrict__ hbuf) {
    int blk = blockIdx.x;
    int b = blk / (LSEQ / 16);
    int l0 = (blk % (LSEQ / 16)) * 16;
    int t = threadIdx.x;
    __shared__ float xs[16][DIN];
    ((float4*)&xs[0][0])[t] = ((const float4*)(x + ((size_t)b * LSEQ + l0) * DIN))[t];
    float wr[DIN];
    const float4* wp4 = (const float4*)(w + (size_t)t * DIN);
#pragma unroll
    for (int i = 0; i < DIN / 4; i++) {
        float4 v = wp4[i];
        wr[4 * i] = v.x; wr[4 * i + 1] = v.y; wr[4 * i + 2] = v.z; wr[4 * i + 3] = v.w;
    }
    float bz = bias[t];
    __syncthreads();
#pragma unroll 4
    for (int l = 0; l < 16; l++) {
        float acc = bz;
#pragma unroll
        for (int i = 0; i < DIN; i++) acc = fmaf(wr[i], xs[l][i], acc);
        hbuf[((size_t)b * LSEQ + l0 + l) * NH + t] = acc;
    }
}

// ---------------- T1: hbuf f32 [b][l][h] -> u_t bf16 [h][bc][j] ----------------
__global__ void __launch_bounds__(256, 2)
s4w_t1(const float* __restrict__ hbuf, ushort* __restrict__ u_t) {
    int bc = blockIdx.x;              // b*32 + c
    int ht = blockIdx.y;              // 0..3
    int b = bc >> 5, c = bc & 31;
    int t = threadIdx.x;
    __shared__ float tile[64][65];    // [j][h']
    const float* src = hbuf + ((size_t)(b * LSEQ + c * 64)) * NH + ht * 64;
    int jr = t >> 4, h4 = t & 15;
#pragma unroll
    for (int p = 0; p < 4; p++) {
        int j = p * 16 + jr;
        float4 v = *(const float4*)(src + (size_t)j * NH + h4 * 4);
        tile[j][h4 * 4 + 0] = v.x; tile[j][h4 * 4 + 1] = v.y;
        tile[j][h4 * 4 + 2] = v.z; tile[j][h4 * 4 + 3] = v.w;
    }
    __syncthreads();
    int hr = t >> 2, jq = t & 3;
    ushort* dst = u_t + ((size_t)(ht * 64 + hr) * NBC + bc) * 64 + jq * 16;
    short8 o0, o1;
#pragma unroll
    for (int i = 0; i < 8; i++) {
        o0[i] = (short)f2bf(tile[jq * 16 + i][hr]);
        o1[i] = (short)f2bf(tile[jq * 16 + 8 + i][hr]);
    }
    *(short8*)dst = o0;
    *(short8*)(dst + 8) = o1;
}

// ---------------- gemmA: end-states = Vmat_h @ u_chunk  (per h) ----------------
__global__ void __launch_bounds__(256, 2)
s4w_gemmA(const ushort* __restrict__ u_t, const ushort* __restrict__ Vmat,
          ushort* __restrict__ statesbf, int layer) {
    int h = blockIdx.x, nt = blockIdx.y;
    int t = threadIdx.x, wave = t >> 6, lane = t & 63;
    int lm = lane & 15, kg = lane >> 4;
    int n0 = nt * 256 + wave * 64;
    const ushort* Ab = Vmat + (size_t)(layer * NH + h) * 4096;
    const ushort* Bb = u_t + (size_t)h * NBC * 64;
    f32x4 acc[4][4];
#pragma unroll
    for (int i = 0; i < 4; i++)
#pragma unroll
        for (int j = 0; j < 4; j++) acc[i][j] = (f32x4){0.f, 0.f, 0.f, 0.f};
#pragma unroll
    for (int ks = 0; ks < 2; ks++) {
        short8 av[4], bv[4];
#pragma unroll
        for (int mf = 0; mf < 4; mf++)
            av[mf] = *(const short8*)(Ab + (mf * 16 + lm) * 64 + ks * 32 + kg * 8);
#pragma unroll
        for (int nf = 0; nf < 4; nf++)
            bv[nf] = *(const short8*)(Bb + (size_t)(n0 + nf * 16 + lm) * 64 + ks * 32 + kg * 8);
#pragma unroll
        for (int mf = 0; mf < 4; mf++)
#pragma unroll
            for (int nf = 0; nf < 4; nf++)
                acc[mf][nf] = __builtin_amdgcn_mfma_f32_16x16x32_bf16(av[mf], bv[nf], acc[mf][nf], 0, 0, 0);
    }
#pragma unroll
    for (int mf = 0; mf < 4; mf++)
#pragma unroll
        for (int nf = 0; nf < 4; nf++) {
            int col = n0 + nf * 16 + lm;
            int row = mf * 16 + kg * 4;
            short4v pk;
#pragma unroll
            for (int j = 0; j < 4; j++) pk[j] = (short)f2bf(acc[mf][nf][j]);
            *(short4v*)(statesbf + ((size_t)h * NBC + col) * 64 + row) = pk;
        }
}

// ---------------- scan: end-states -> start-states (in place) ----------------
__global__ void s4w_scan(ushort* __restrict__ statesbf,
                         const float* __restrict__ pr_, const float* __restrict__ pi_, int layer) {
    int idx = blockIdx.x * 256 + threadIdx.x;   // h*1024 + b*32 + n
    int n = idx & 31, b = (idx >> 5) & 31, h = idx >> 10;
    float pr = pr_[(size_t)(layer * NH + h) * NN + n];
    float pi = pi_[(size_t)(layer * NH + h) * NN + n];
    float sr = 0.f, si = 0.f;
    ushort* sp = statesbf + ((size_t)h * NBC + b * NCH) * 64 + 2 * n;
    for (int c = 0; c < NCH; c++) {
        uint v = *(const uint*)(sp + (size_t)c * 64);
        float er = bf2f((ushort)(v & 0xffff));
        float ei = bf2f((ushort)(v >> 16));
        *(uint*)(sp + (size_t)c * 64) = (uint)f2bf(sr) | ((uint)f2bf(si) << 16);
        float nsr = pr * sr - pi * si + er;
        float nsi = pr * si + pi * sr + ei;
        sr = nsr; si = nsi;
    }
}

// ---------------- gemmC: y = Lmat_h @ u + Wc_h @ s_start; + Dp*u; GELU; in place ----------------
__global__ void __launch_bounds__(256, 2)
s4w_gemmC(ushort* __restrict__ u_t, const ushort* __restrict__ statesbf,
          const ushort* __restrict__ Lmat, const ushort* __restrict__ Wc,
          const float* __restrict__ Dp, int layer) {
    int h = blockIdx.x, nt = blockIdx.y;
    int t = threadIdx.x, wave = t >> 6, lane = t & 63;
    int lm = lane & 15, kg = lane >> 4;
    int n0 = nt * 256 + wave * 64;
    const ushort* La = Lmat + (size_t)(layer * NH + h) * 4096;
    const ushort* Wa = Wc + (size_t)(layer * NH + h) * 4096;
    const ushort* Ub = u_t + (size_t)h * NBC * 64;
    const ushort* Sb = statesbf + (size_t)h * NBC * 64;
    f32x4 acc[4][4];
#pragma unroll
    for (int i = 0; i < 4; i++)
#pragma unroll
        for (int j = 0; j < 4; j++) acc[i][j] = (f32x4){0.f, 0.f, 0.f, 0.f};
#pragma unroll
    for (int ks = 0; ks < 2; ks++) {
        short8 av[4], bv[4];
#pragma unroll
        for (int mf = 0; mf < 4; mf++)
            av[mf] = *(const short8*)(La + (mf * 16 + lm) * 64 + ks * 32 + kg * 8);
#pragma unroll
        for (int nf = 0; nf < 4; nf++)
            bv[nf] = *(const short8*)(Ub + (size_t)(n0 + nf * 16 + lm) * 64 + ks * 32 + kg * 8);
#pragma unroll
        for (int mf = 0; mf < 4; mf++)
#pragma unroll
            for (int nf = 0; nf < 4; nf++)
                acc[mf][nf] = __builtin_amdgcn_mfma_f32_16x16x32_bf16(av[mf], bv[nf], acc[mf][nf], 0, 0, 0);
    }
#pragma unroll
    for (int ks = 0; ks < 2; ks++) {
        short8 av[4], bv[4];
#pragma unroll
        for (int mf = 0; mf < 4; mf++)
            av[mf] = *(const short8*)(Wa + (mf * 16 + lm) * 64 + ks * 32 + kg * 8);
#pragma unroll
        for (int nf = 0; nf < 4; nf++)
            bv[nf] = *(const short8*)(Sb + (size_t)(n0 + nf * 16 + lm) * 64 + ks * 32 + kg * 8);
#pragma unroll
        for (int mf = 0; mf < 4; mf++)
#pragma unroll
            for (int nf = 0; nf < 4; nf++)
                acc[mf][nf] = __builtin_amdgcn_mfma_f32_16x16x32_bf16(av[mf], bv[nf], acc[mf][nf], 0, 0, 0);
    }
    float dp = Dp[layer * NH + h];
#pragma unroll
    for (int mf = 0; mf < 4; mf++)
#pragma unroll
        for (int nf = 0; nf < 4; nf++) {
            int col = n0 + nf * 16 + lm;
            int row = mf * 16 + kg * 4;
            ushort* base = u_t + ((size_t)h * NBC + col) * 64 + row;
            short4v uv = *(const short4v*)base;
            short4v yo;
#pragma unroll
            for (int j = 0; j < 4; j++) {
                float u = bf2f((ushort)uv[j]);
                float y = acc[mf][nf][j] + dp * u;
                float g = 0.5f * y * (1.0f + erff(y * 0.70710678118f));
                yo[j] = (short)f2bf(g);
            }
            *(short4v*)base = yo;
        }
}

// ---------------- T2: y_t bf16 [h][bc][j] -> ybf bf16 [b][l][h] ----------------
__global__ void __launch_bounds__(256, 2)
s4w_t2(const ushort* __restrict__ y_t, ushort* __restrict__ ybf) {
    int bc = blockIdx.x;
    int ht = blockIdx.y;
    int b = bc >> 5, c = bc & 31;
    int t = threadIdx.x;
    __shared__ ushort tile[64][65];   // [h'][j]
    int hr = t >> 2, jq = t & 3;
    const ushort* src = y_t + ((size_t)(ht * 64 + hr) * NBC + bc) * 64 + jq * 16;
    short8 i0 = *(const short8*)src;
    short8 i1 = *(const short8*)(src + 8);
#pragma unroll
    for (int i = 0; i < 8; i++) {
        tile[hr][jq * 16 + i] = (ushort)i0[i];
        tile[hr][jq * 16 + 8 + i] = (ushort)i1[i];
    }
    __syncthreads();
    int jr = t >> 2, hq = t & 3;
    ushort* dst = ybf + ((size_t)(b * LSEQ + c * 64 + jr)) * NH + ht * 64 + hq * 16;
    short8 o0, o1;
#pragma unroll
    for (int i = 0; i < 8; i++) {
        o0[i] = (short)tile[hq * 16 + i][jr];
        o1[i] = (short)tile[hq * 16 + 8 + i][jr];
    }
    *(short8*)dst = o0;
    *(short8*)(dst + 8) = o1;
}

// ---------------- proj v2: LDS-staged y, LT=32, 4 blocks/CU ----------------
__global__ void __launch_bounds__(256, 4)
s4w_proj_mfma(const ushort* __restrict__ ybf, float* __restrict__ hbuf,
              const ushort* __restrict__ wbf, const float* __restrict__ ob,
              const float* __restrict__ lnw, const float* __restrict__ lnb, int layer) {
    int b = blockIdx.x;
    int n0 = blockIdx.y * LT;
    int t = threadIdx.x;
    int wave = t >> 6, lane = t & 63;
    int lm = lane & 15, kg = lane >> 4;

    // ys (bf16 staged y tile) and glu (f32 epilogue) alias the same LDS
    __shared__ __align__(16) char sbuf[LT * (NH + 1) * 4];     // 32*257*4 = 32896 B
    typedef ushort ysrow[NH + 8];
    typedef float glurow[NH + 1];
    ysrow* ys = (ysrow*)sbuf;        // 32 * 264 * 2 = 16896 B (fits)
    glurow* glu = (glurow*)sbuf;
    __shared__ float ps[256], pq[256];
    __shared__ float mean_s[LT], rstd_s[LT];

    // ---- stage y tile: contiguous 16 KB, fully coalesced ----
    const ushort* ysrc = ybf + ((size_t)b * LSEQ + n0) * NH;
#pragma unroll
    for (int p = 0; p < 4; p++) {
        int cid = p * 256 + t;         // 1024 chunks of 16 B
        int row = cid >> 5, ch = cid & 31;
        *(short8*)&ys[row][ch * 8] = *(const short8*)(ysrc + (size_t)row * NH + ch * 8);
    }
    __syncthreads();

    f32x4 acc[8][2];
#pragma unroll
    for (int i = 0; i < 8; i++)
#pragma unroll
        for (int j = 0; j < 2; j++) acc[i][j] = (f32x4){0.f, 0.f, 0.f, 0.f};

    const ushort* wp = wbf + (size_t)layer * 512 * NH;

#pragma unroll
    for (int ks = 0; ks < 8; ks++) {
        short8 bv[2];
#pragma unroll
        for (int ni = 0; ni < 2; ni++)
            bv[ni] = *(const short8*)&ys[ni * 16 + lm][ks * 32 + kg * 8];
#pragma unroll
        for (int mi = 0; mi < 8; mi++) {
            int o = (mi < 4 ? wave * 64 + mi * 16 : 256 + wave * 64 + (mi - 4) * 16) + lm;
            short8 av = *(const short8*)(wp + (size_t)o * NH + ks * 32 + kg * 8);
#pragma unroll
            for (int ni = 0; ni < 2; ni++)
                acc[mi][ni] = __builtin_amdgcn_mfma_f32_16x16x32_bf16(av, bv[ni], acc[mi][ni], 0, 0, 0);
        }
    }
    __syncthreads();   // all ys reads done before glu overwrites sbuf

    // ---- epilogue: bias + GLU -> glu LDS ----
#pragma unroll
    for (int mi = 0; mi < 4; mi++) {
        int o = wave * 64 + mi * 16 + kg * 4;
        float oba0 = ob[layer * 2 * NH + o],     oba1 = ob[layer * 2 * NH + o + 1];
        float oba2 = ob[layer * 2 * NH + o + 2], oba3 = ob[layer * 2 * NH + o + 3];
        float obg0 = ob[layer * 2 * NH + NH + o],     obg1 = ob[layer * 2 * NH + NH + o + 1];
        float obg2 = ob[layer * 2 * NH + NH + o + 2], obg3 = ob[layer * 2 * NH + NH + o + 3];
        float oba[4] = { oba0, oba1, oba2, oba3 };
        float obg[4] = { obg0, obg1, obg2, obg3 };
#pragma unroll
        for (int ni = 0; ni < 2; ni++) {
            int l = ni * 16 + lm;
#pragma unroll
            for (int j = 0; j < 4; j++) {
                float a = acc[mi][ni][j] + oba[j];
                float g = acc[mi + 4][ni][j] + obg[j];
                float v = a * (1.0f / (1.0f + expf(-g)));
                glu[l][o + j] = v;
            }
        }
    }
    __syncthreads();

    // ---- residual add (coalesced) ----
    const size_t hbase = ((size_t)b * LSEQ + n0) * NH;
#pragma unroll 4
    for (int l = 0; l < LT; l++)
        glu[l][t] += hbuf[hbase + (size_t)l * NH + t];
    __syncthreads();

    // ---- LN stats: 256 threads = 32 l x 8 segments of 32 channels ----
    {
        int l = t & 31, seg = t >> 5;
        float s = 0.f, q = 0.f;
#pragma unroll
        for (int i = 0; i < 32; i++) {
            float v = glu[l][seg * 32 + i];
            s += v; q = fmaf(v, v, q);
        }
        ps[t] = s; pq[t] = q;
    }
    __syncthreads();
    if (t < LT) {
        float S = 0.f, Q = 0.f;
#pragma unroll
        for (int k = 0; k < 8; k++) { S += ps[t + 32 * k]; Q += pq[t + 32 * k]; }
        float m = S * (1.0f / NH);
        float v = Q * (1.0f / NH) - m * m;
        mean_s[t] = m; rstd_s[t] = rsqrtf(v + LN_EPS);
    }
    __syncthreads();

    float lw = lnw[layer * NH + t], lb = lnb[layer * NH + t];
#pragma unroll 4
    for (int l = 0; l < LT; l++) {
        float v = (glu[l][t] - mean_s[l]) * rstd_s[l] * lw + lb;
        hbuf[hbase + (size_t)l * NH + t] = v;
    }
}

// ---------------- head MLP: one wave per output element ----------------
__global__ void __launch_bounds__(256, 4)
s4w_mlp_wave(const float* __restrict__ in, size_t in_bstride,
             const float* __restrict__ w, const float* __restrict__ bias,
             float* __restrict__ out, int K, int N, int do_relu) {
    int wid = (blockIdx.x * 256 + threadIdx.x) >> 6;
    int lane = threadIdx.x & 63;
    if (wid >= NB * N) return;
    int b = wid / N, o = wid % N;
    const float* ip = in + (size_t)b * in_bstride;
    const float* wp = w + (size_t)o * K;
    float acc = 0.f;
    for (int k = lane; k < K; k += 64) acc = fmaf(wp[k], ip[k], acc);
#pragma unroll
    for (int off = 32; off > 0; off >>= 1) acc += __shfl_xor(acc, off, 64);
    if (lane == 0) {
        float v = acc + bias[o];
        out[(size_t)b * N + o] = do_relu ? fmaxf(v, 0.f) : v;
    }
}

extern "C" void kernel_launch(void* const* d_in, const int* in_sizes, int n_in,
                              void* d_out, int out_size, void* d_ws, size_t ws_size,
                              hipStream_t stream) {
    const float* x          = (const float*)d_in[0];
    const float* enc_w      = (const float*)d_in[1];
    const float* enc_b      = (const float*)d_in[2];
    const float* log_dt     = (const float*)d_in[3];
    const float* C_re       = (const float*)d_in[4];
    const float* C_im       = (const float*)d_in[5];
    const float* log_A_real = (const float*)d_in[6];
    const float* A_imag     = (const float*)d_in[7];
    const float* Dp         = (const float*)d_in[8];
    const float* out_w      = (const float*)d_in[9];
    const float* out_b      = (const float*)d_in[10];
    const float* ln_w       = (const float*)d_in[11];
    const float* ln_b       = (const float*)d_in[12];
    const float* lin1_w     = (const float*)d_in[13];
    const float* lin1_b     = (const float*)d_in[14];
    const float* lin2_w     = (const float*)d_in[15];
    const float* lin2_b     = (const float*)d_in[16];
    const float* lin3_w     = (const float*)d_in[17];
    const float* lin3_b     = (const float*)d_in[18];
    float* outp = (float*)d_out;

    float* ws = (float*)d_ws;
    size_t off = 0;
    float* hbuf = ws + off;              off += (size_t)NB * LSEQ * NH;
    ushort* u_t = (ushort*)(ws + off);   off += (size_t)NH * NBC * 64 / 2;
    ushort* statesbf = (ushort*)(ws + off); off += (size_t)NH * NBC * 64 / 2;
    ushort* wbf = (ushort*)(ws + off);   off += (size_t)NLAY * 2 * NH * NH / 2;
    ushort* Lmat = (ushort*)(ws + off);  off += (size_t)NLAY * NH * 4096 / 2;
    ushort* Wc   = (ushort*)(ws + off);  off += (size_t)NLAY * NH * 4096 / 2;
    ushort* Vmat = (ushort*)(ws + off);  off += (size_t)NLAY * NH * 4096 / 2;
    float* pr_ = ws + off;               off += NLAY * NH * NN;
    float* pi_ = ws + off;               off += NLAY * NH * NN;
    float* t1  = ws + off;               off += NB * ML1;
    float* t2  = ws + off;               off += NB * ML2;
    ushort* ybf = statesbf;   // reuse: states consumed by gemmC before T2 writes ybf

    s4w_coef<<<(NLAY * NH * NN + 255) / 256, 256, 0, stream>>>(
        log_dt, log_A_real, A_imag, pr_, pi_);
    s4w_matprep<<<NLAY * NH, 64, 0, stream>>>(
        log_dt, C_re, C_im, log_A_real, A_imag, Lmat, Wc, Vmat);
    s4w_wprep<<<(NLAY * 2 * NH * NH) / 256, 256, 0, stream>>>(out_w, wbf);

    s4w_enc<<<NB * (LSEQ / 16), 256, 0, stream>>>(x, enc_w, enc_b, hbuf);

    for (int layer = 0; layer < NLAY; layer++) {
        s4w_t1<<<dim3(NBC, 4), 256, 0, stream>>>(hbuf, u_t);
        s4w_gemmA<<<dim3(NH, 4), 256, 0, stream>>>(u_t, Vmat, statesbf, layer);
        s4w_scan<<<(NH * NB * NN) / 256, 256, 0, stream>>>(statesbf, pr_, pi_, layer);
        s4w_gemmC<<<dim3(NH, 4), 256, 0, stream>>>(u_t, statesbf, Lmat, Wc, Dp, layer);
        s4w_t2<<<dim3(NBC, 4), 256, 0, stream>>>(u_t, ybf);
        s4w_proj_mfma<<<dim3(NB, LSEQ / LT), 256, 0, stream>>>(ybf, hbuf, wbf, out_b, ln_w, ln_b, layer);
    }

    s4w_mlp_wave<<<(NB * ML1 + 3) / 4, 256, 0, stream>>>(
        hbuf + (size_t)(LSEQ - 1) * NH, (size_t)LSEQ * NH, lin1_w, lin1_b, t1, NH, ML1, 1);
    s4w_mlp_wave<<<(NB * ML2 + 3) / 4, 256, 0, stream>>>(
        t1, ML1, lin2_w, lin2_b, t2, ML1, ML2, 1);
    s4w_mlp_wave<<<(NB * MOUT + 3) / 4, 256, 0, stream>>>(
        t2, ML2, lin3_w, lin3_b, outp, ML2, MOUT, 0);
}

// Round 12
// 481.141 us; speedup vs baseline: 1.0484x; 1.0484x over previous
//
#include <hip/hip_runtime.h>
#include <hip/hip_bf16.h>
#include <math.h>

#define NB 32
#define LSEQ 2048
#define DIN 64
#define NH 256
#define NN 32
#define NLAY 2
#define NCH 32
#define TCH 64    // LSEQ/NCH
#define NBC (NB*NCH)          // 1024 columns
#define LT 32                 // proj l-tile
#define ML1 350
#define ML2 400
#define MOUT 1024
#define LN_EPS 1e-5f

typedef short short8 __attribute__((ext_vector_type(8)));
typedef short short4v __attribute__((ext_vector_type(4)));
typedef float f32x4 __attribute__((ext_vector_type(4)));

__device__ __forceinline__ float bf2f(ushort u) {
    union { uint i; float f; } v; v.i = ((uint)u) << 16; return v.f;
}
__device__ __forceinline__ ushort f2bf(float f) {
    __hip_bfloat16 h = __float2bfloat16(f);
    return *reinterpret_cast<ushort*>(&h);
}

// ---------------- coefficient prep (E^64 for scan) ----------------
__global__ void s4w_coef(const float* __restrict__ log_dt,
                         const float* __restrict__ log_A_real, const float* __restrict__ A_imag,
                         float* __restrict__ pr_, float* __restrict__ pi_) {
    int idx = blockIdx.x * 256 + threadIdx.x;
    if (idx >= NLAY * NH * NN) return;
    int h = (idx / NN) % NH;
    int l = idx / (NN * NH);
    float dt = expf(log_dt[l * NH + h]);
    float ar = -expf(log_A_real[idx]);
    float ai = A_imag[idx];
    double dre = (double)(ar * dt), dim = (double)(ai * dt);
    double exT = exp(dre * (double)TCH);
    double ang = dim * (double)TCH;
    pr_[idx] = (float)(exT * cos(ang));
    pi_[idx] = (float)(exT * sin(ang));
}

// ---------------- matrix prep: Lmat (causal kernel), Wc (carry), Vmat (end-state) ----------------
__global__ void s4w_matprep(const float* __restrict__ log_dt,
                            const float* __restrict__ C_re, const float* __restrict__ C_im,
                            const float* __restrict__ log_A_real, const float* __restrict__ A_imag,
                            ushort* __restrict__ Lmat, ushort* __restrict__ Wc,
                            ushort* __restrict__ Vmat) {
    int lh = blockIdx.x;          // layer*NH + h
    int t = threadIdx.x;          // 0..63
    __shared__ float ksh[64];
    float dt = expf(log_dt[lh]);
    float kacc = 0.f;
    for (int n = 0; n < NN; n++) {
        int idx = lh * NN + n;
        float ar = -expf(log_A_real[idx]);
        float ai = A_imag[idx];
        float dre = ar * dt, dim = ai * dt;
        float e1 = expf(dre);
        float er1 = e1 * cosf(dim), ei1 = e1 * sinf(dim);
        float den = ar * ar + ai * ai;
        float qr = ((er1 - 1.f) * ar + ei1 * ai) / den;
        float qi = (ei1 * ar - (er1 - 1.f) * ai) / den;
        float cr = C_re[idx], ci = C_im[idx];
        float ctr = 2.f * (cr * qr - ci * qi);
        float cti = 2.f * (cr * qi + ci * qr);
        float ed = expf(dre * (float)t);
        float angd = dim * (float)t;
        float erd = ed * cosf(angd), eid = ed * sinf(angd);
        kacc += ctr * erd - cti * eid;
        float ew = expf(dre * (float)(t + 1));
        float angw = dim * (float)(t + 1);
        float ewr = ew * cosf(angw), ewi = ew * sinf(angw);
        float wr = ctr * ewr - cti * ewi;
        float wi = ctr * ewi + cti * ewr;
        Wc[(size_t)lh * 4096 + t * 64 + 2 * n]     = f2bf(wr);
        Wc[(size_t)lh * 4096 + t * 64 + 2 * n + 1] = f2bf(-wi);
        float ev = expf(dre * (float)(63 - t));
        float angv = dim * (float)(63 - t);
        Vmat[(size_t)lh * 4096 + (2 * n) * 64 + t]     = f2bf(ev * cosf(angv));
        Vmat[(size_t)lh * 4096 + (2 * n + 1) * 64 + t] = f2bf(ev * sinf(angv));
    }
    ksh[t] = kacc;
    __syncthreads();
    for (int j = 0; j < 64; j++)
        Lmat[(size_t)lh * 4096 + t * 64 + j] = (j <= t) ? f2bf(ksh[t - j]) : (ushort)0;
}

// ---------------- weight prep: out_w -> bf16 ----------------
__global__ void s4w_wprep(const float* __restrict__ ow, ushort* __restrict__ wbf) {
    int idx = blockIdx.x * 256 + threadIdx.x;
    wbf[idx] = f2bf(ow[idx]);
}

// ---------------- encoder ----------------
__global__ void __launch_bounds__(256, 2)
s4w_enc(const float* __restrict__ x, const float* __restrict__ w,
        const float* __restrict__ bias, float* __restrict__ hbuf) {
    int blk = blockIdx.x;
    int b = blk / (LSEQ / 16);
    int l0 = (blk % (LSEQ / 16)) * 16;
    int t = threadIdx.x;
    __shared__ float xs[16][DIN];
    ((float4*)&xs[0][0])[t] = ((const float4*)(x + ((size_t)b * LSEQ + l0) * DIN))[t];
    float wr[DIN];
    const float4* wp4 = (const float4*)(w + (size_t)t * DIN);
#pragma unroll
    for (int i = 0; i < DIN / 4; i++) {
        float4 v = wp4[i];
        wr[4 * i] = v.x; wr[4 * i + 1] = v.y; wr[4 * i + 2] = v.z; wr[4 * i + 3] = v.w;
    }
    float bz = bias[t];
    __syncthreads();
#pragma unroll 4
    for (int l = 0; l < 16; l++) {
        float acc = bz;
#pragma unroll
        for (int i = 0; i < DIN; i++) acc = fmaf(wr[i], xs[l][i], acc);
        hbuf[((size_t)b * LSEQ + l0 + l) * NH + t] = acc;
    }
}

// ---------------- T1: hbuf f32 [b][l][h] -> u_t bf16 [h][bc][j] ----------------
__global__ void __launch_bounds__(256, 2)
s4w_t1(const float* __restrict__ hbuf, ushort* __restrict__ u_t) {
    int bc = blockIdx.x;              // b*32 + c
    int ht = blockIdx.y;              // 0..3
    int b = bc >> 5, c = bc & 31;
    int t = threadIdx.x;
    __shared__ float tile[64][65];    // [j][h']
    const float* src = hbuf + ((size_t)(b * LSEQ + c * 64)) * NH + ht * 64;
    int jr = t >> 4, h4 = t & 15;
#pragma unroll
    for (int p = 0; p < 4; p++) {
        int j = p * 16 + jr;
        float4 v = *(const float4*)(src + (size_t)j * NH + h4 * 4);
        tile[j][h4 * 4 + 0] = v.x; tile[j][h4 * 4 + 1] = v.y;
        tile[j][h4 * 4 + 2] = v.z; tile[j][h4 * 4 + 3] = v.w;
    }
    __syncthreads();
    int hr = t >> 2, jq = t & 3;
    ushort* dst = u_t + ((size_t)(ht * 64 + hr) * NBC + bc) * 64 + jq * 16;
    short8 o0, o1;
#pragma unroll
    for (int i = 0; i < 8; i++) {
        o0[i] = (short)f2bf(tile[jq * 16 + i][hr]);
        o1[i] = (short)f2bf(tile[jq * 16 + 8 + i][hr]);
    }
    *(short8*)dst = o0;
    *(short8*)(dst + 8) = o1;
}

// ---------------- gemmA: end-states = Vmat_h @ u_chunk  (per h) ----------------
__global__ void __launch_bounds__(256, 2)
s4w_gemmA(const ushort* __restrict__ u_t, const ushort* __restrict__ Vmat,
          ushort* __restrict__ statesbf, int layer) {
    int h = blockIdx.x, nt = blockIdx.y;
    int t = threadIdx.x, wave = t >> 6, lane = t & 63;
    int lm = lane & 15, kg = lane >> 4;
    int n0 = nt * 256 + wave * 64;
    const ushort* Ab = Vmat + (size_t)(layer * NH + h) * 4096;
    const ushort* Bb = u_t + (size_t)h * NBC * 64;
    f32x4 acc[4][4];
#pragma unroll
    for (int i = 0; i < 4; i++)
#pragma unroll
        for (int j = 0; j < 4; j++) acc[i][j] = (f32x4){0.f, 0.f, 0.f, 0.f};
#pragma unroll
    for (int ks = 0; ks < 2; ks++) {
        short8 av[4], bv[4];
#pragma unroll
        for (int mf = 0; mf < 4; mf++)
            av[mf] = *(const short8*)(Ab + (mf * 16 + lm) * 64 + ks * 32 + kg * 8);
#pragma unroll
        for (int nf = 0; nf < 4; nf++)
            bv[nf] = *(const short8*)(Bb + (size_t)(n0 + nf * 16 + lm) * 64 + ks * 32 + kg * 8);
#pragma unroll
        for (int mf = 0; mf < 4; mf++)
#pragma unroll
            for (int nf = 0; nf < 4; nf++)
                acc[mf][nf] = __builtin_amdgcn_mfma_f32_16x16x32_bf16(av[mf], bv[nf], acc[mf][nf], 0, 0, 0);
    }
#pragma unroll
    for (int mf = 0; mf < 4; mf++)
#pragma unroll
        for (int nf = 0; nf < 4; nf++) {
            int col = n0 + nf * 16 + lm;
            int row = mf * 16 + kg * 4;
            short4v pk;
#pragma unroll
            for (int j = 0; j < 4; j++) pk[j] = (short)f2bf(acc[mf][nf][j]);
            *(short4v*)(statesbf + ((size_t)h * NBC + col) * 64 + row) = pk;
        }
}

// ---------------- scan: end-states -> start-states (in place) ----------------
__global__ void s4w_scan(ushort* __restrict__ statesbf,
                         const float* __restrict__ pr_, const float* __restrict__ pi_, int layer) {
    int idx = blockIdx.x * 256 + threadIdx.x;   // h*1024 + b*32 + n
    int n = idx & 31, b = (idx >> 5) & 31, h = idx >> 10;
    float pr = pr_[(size_t)(layer * NH + h) * NN + n];
    float pi = pi_[(size_t)(layer * NH + h) * NN + n];
    float sr = 0.f, si = 0.f;
    ushort* sp = statesbf + ((size_t)h * NBC + b * NCH) * 64 + 2 * n;
    for (int c = 0; c < NCH; c++) {
        uint v = *(const uint*)(sp + (size_t)c * 64);
        float er = bf2f((ushort)(v & 0xffff));
        float ei = bf2f((ushort)(v >> 16));
        *(uint*)(sp + (size_t)c * 64) = (uint)f2bf(sr) | ((uint)f2bf(si) << 16);
        float nsr = pr * sr - pi * si + er;
        float nsi = pr * si + pi * sr + ei;
        sr = nsr; si = nsi;
    }
}

// ---------------- gemmC: y = Lmat_h @ u + Wc_h @ s_start; + Dp*u; GELU; in place ----------------
__global__ void __launch_bounds__(256, 2)
s4w_gemmC(ushort* __restrict__ u_t, const ushort* __restrict__ statesbf,
          const ushort* __restrict__ Lmat, const ushort* __restrict__ Wc,
          const float* __restrict__ Dp, int layer) {
    int h = blockIdx.x, nt = blockIdx.y;
    int t = threadIdx.x, wave = t >> 6, lane = t & 63;
    int lm = lane & 15, kg = lane >> 4;
    int n0 = nt * 256 + wave * 64;
    const ushort* La = Lmat + (size_t)(layer * NH + h) * 4096;
    const ushort* Wa = Wc + (size_t)(layer * NH + h) * 4096;
    const ushort* Ub = u_t + (size_t)h * NBC * 64;
    const ushort* Sb = statesbf + (size_t)h * NBC * 64;
    f32x4 acc[4][4];
#pragma unroll
    for (int i = 0; i < 4; i++)
#pragma unroll
        for (int j = 0; j < 4; j++) acc[i][j] = (f32x4){0.f, 0.f, 0.f, 0.f};
#pragma unroll
    for (int ks = 0; ks < 2; ks++) {
        short8 av[4], bv[4];
#pragma unroll
        for (int mf = 0; mf < 4; mf++)
            av[mf] = *(const short8*)(La + (mf * 16 + lm) * 64 + ks * 32 + kg * 8);
#pragma unroll
        for (int nf = 0; nf < 4; nf++)
            bv[nf] = *(const short8*)(Ub + (size_t)(n0 + nf * 16 + lm) * 64 + ks * 32 + kg * 8);
#pragma unroll
        for (int mf = 0; mf < 4; mf++)
#pragma unroll
            for (int nf = 0; nf < 4; nf++)
                acc[mf][nf] = __builtin_amdgcn_mfma_f32_16x16x32_bf16(av[mf], bv[nf], acc[mf][nf], 0, 0, 0);
    }
#pragma unroll
    for (int ks = 0; ks < 2; ks++) {
        short8 av[4], bv[4];
#pragma unroll
        for (int mf = 0; mf < 4; mf++)
            av[mf] = *(const short8*)(Wa + (mf * 16 + lm) * 64 + ks * 32 + kg * 8);
#pragma unroll
        for (int nf = 0; nf < 4; nf++)
            bv[nf] = *(const short8*)(Sb + (size_t)(n0 + nf * 16 + lm) * 64 + ks * 32 + kg * 8);
#pragma unroll
        for (int mf = 0; mf < 4; mf++)
#pragma unroll
            for (int nf = 0; nf < 4; nf++)
                acc[mf][nf] = __builtin_amdgcn_mfma_f32_16x16x32_bf16(av[mf], bv[nf], acc[mf][nf], 0, 0, 0);
    }
    float dp = Dp[layer * NH + h];
#pragma unroll
    for (int mf = 0; mf < 4; mf++)
#pragma unroll
        for (int nf = 0; nf < 4; nf++) {
            int col = n0 + nf * 16 + lm;
            int row = mf * 16 + kg * 4;
            ushort* base = u_t + ((size_t)h * NBC + col) * 64 + row;
            short4v uv = *(const short4v*)base;
            short4v yo;
#pragma unroll
            for (int j = 0; j < 4; j++) {
                float u = bf2f((ushort)uv[j]);
                float y = acc[mf][nf][j] + dp * u;
                float g = 0.5f * y * (1.0f + erff(y * 0.70710678118f));
                yo[j] = (short)f2bf(g);
            }
            *(short4v*)base = yo;
        }
}

// ---------------- T2: y_t bf16 [h][bc][j] -> ybf bf16 [b][l][h] ----------------
__global__ void __launch_bounds__(256, 2)
s4w_t2(const ushort* __restrict__ y_t, ushort* __restrict__ ybf) {
    int bc = blockIdx.x;
    int ht = blockIdx.y;
    int b = bc >> 5, c = bc & 31;
    int t = threadIdx.x;
    __shared__ ushort tile[64][65];   // [h'][j]
    int hr = t >> 2, jq = t & 3;
    const ushort* src = y_t + ((size_t)(ht * 64 + hr) * NBC + bc) * 64 + jq * 16;
    short8 i0 = *(const short8*)src;
    short8 i1 = *(const short8*)(src + 8);
#pragma unroll
    for (int i = 0; i < 8; i++) {
        tile[hr][jq * 16 + i] = (ushort)i0[i];
        tile[hr][jq * 16 + 8 + i] = (ushort)i1[i];
    }
    __syncthreads();
    int jr = t >> 2, hq = t & 3;
    ushort* dst = ybf + ((size_t)(b * LSEQ + c * 64 + jr)) * NH + ht * 64 + hq * 16;
    short8 o0, o1;
#pragma unroll
    for (int i = 0; i < 8; i++) {
        o0[i] = (short)tile[hq * 16 + i][jr];
        o1[i] = (short)tile[hq * 16 + 8 + i][jr];
    }
    *(short8*)dst = o0;
    *(short8*)(dst + 8) = o1;
}

// ---------------- proj v3: 8 waves, register-resident W, 8 l-tiles per block ----------------
// Wave w owns o in [32w,32w+32) (a-half) and [256+32w, 256+32w+32) (g-half).
// W fragments (4 frag-rows x 8 k-steps = 128 VGPR) loaded ONCE, reused for 8 tiles.
__global__ void __launch_bounds__(512, 2)
s4w_proj_mfma(const ushort* __restrict__ ybf, float* __restrict__ hbuf,
              const ushort* __restrict__ wbf, const float* __restrict__ ob,
              const float* __restrict__ lnw, const float* __restrict__ lnb, int layer) {
    int b = blockIdx.x;
    int chunk = blockIdx.y;            // 8 chunks of 256 l
    int t = threadIdx.x;
    int wave = t >> 6, lane = t & 63;
    int lm = lane & 15, kg = lane >> 4;

    __shared__ __align__(16) char sbuf[LT * (NH + 1) * 4];   // 32896 B, ys/glu alias
    typedef ushort ysrow[NH + 8];
    typedef float glurow[NH + 1];
    ysrow* ys = (ysrow*)sbuf;
    glurow* glu = (glurow*)sbuf;
    __shared__ float ps[512], pq[512];
    __shared__ float mean_s[LT], rstd_s[LT];

    const ushort* wp = wbf + (size_t)layer * 512 * NH;

    // ---- register-resident W fragments (loaded once) ----
    short8 av[4][8];
#pragma unroll
    for (int mi = 0; mi < 4; mi++) {
        int o = (mi < 2 ? wave * 32 + mi * 16 : 256 + wave * 32 + (mi - 2) * 16) + lm;
#pragma unroll
        for (int ks = 0; ks < 8; ks++)
            av[mi][ks] = *(const short8*)(wp + (size_t)o * NH + ks * 32 + kg * 8);
    }

    float oba[2][4], obg[2][4];
#pragma unroll
    for (int mi = 0; mi < 2; mi++)
#pragma unroll
        for (int j = 0; j < 4; j++) {
            int o = wave * 32 + mi * 16 + kg * 4 + j;
            oba[mi][j] = ob[layer * 2 * NH + o];
            obg[mi][j] = ob[layer * 2 * NH + NH + o];
        }
    int hch = t & 255, lp = t >> 8;
    float lw = lnw[layer * NH + hch], lb = lnb[layer * NH + hch];

    for (int tile = 0; tile < 8; tile++) {
        int l0 = chunk * 256 + tile * LT;
        const size_t hbase = ((size_t)b * LSEQ + l0) * NH;

        // ---- stage y tile (16 KB, coalesced) ----
        const ushort* ysrc = ybf + ((size_t)b * LSEQ + l0) * NH;
#pragma unroll
        for (int p = 0; p < 2; p++) {
            int cid = p * 512 + t;
            int row = cid >> 5, ch = cid & 31;
            *(short8*)&ys[row][ch * 8] = *(const short8*)(ysrc + (size_t)row * NH + ch * 8);
        }
        __syncthreads();

        f32x4 acc[4][2];
#pragma unroll
        for (int i = 0; i < 4; i++)
#pragma unroll
            for (int j = 0; j < 2; j++) acc[i][j] = (f32x4){0.f, 0.f, 0.f, 0.f};

#pragma unroll
        for (int ks = 0; ks < 8; ks++) {
            short8 bv[2];
#pragma unroll
            for (int ni = 0; ni < 2; ni++)
                bv[ni] = *(const short8*)&ys[ni * 16 + lm][ks * 32 + kg * 8];
#pragma unroll
            for (int mi = 0; mi < 4; mi++)
#pragma unroll
                for (int ni = 0; ni < 2; ni++)
                    acc[mi][ni] = __builtin_amdgcn_mfma_f32_16x16x32_bf16(av[mi][ks], bv[ni], acc[mi][ni], 0, 0, 0);
        }
        __syncthreads();   // ys reads done before glu overwrite

        // ---- epilogue: bias + GLU -> glu ----
#pragma unroll
        for (int mi = 0; mi < 2; mi++)
#pragma unroll
            for (int ni = 0; ni < 2; ni++)
#pragma unroll
                for (int j = 0; j < 4; j++) {
                    float a = acc[mi][ni][j] + oba[mi][j];
                    float g = acc[mi + 2][ni][j] + obg[mi][j];
                    float v = a * (1.0f / (1.0f + expf(-g)));
                    glu[ni * 16 + lm][wave * 32 + mi * 16 + kg * 4 + j] = v;
                }
        __syncthreads();

        // ---- residual add ----
#pragma unroll
        for (int lq = 0; lq < 16; lq++) {
            int l = lq * 2 + lp;
            glu[l][hch] += hbuf[hbase + (size_t)l * NH + hch];
        }
        __syncthreads();

        // ---- LN stats: 512 threads = 32 l x 16 segments of 16 ch ----
        {
            int l = t & 31, seg = t >> 5;
            float s = 0.f, q = 0.f;
#pragma unroll
            for (int i = 0; i < 16; i++) {
                float v = glu[l][seg * 16 + i];
                s += v; q = fmaf(v, v, q);
            }
            ps[t] = s; pq[t] = q;
        }
        __syncthreads();
        if (t < LT) {
            float S = 0.f, Q = 0.f;
#pragma unroll
            for (int k = 0; k < 16; k++) { S += ps[k * 32 + t]; Q += pq[k * 32 + t]; }
            float m = S * (1.0f / NH);
            float v = Q * (1.0f / NH) - m * m;
            mean_s[t] = m; rstd_s[t] = rsqrtf(v + LN_EPS);
        }
        __syncthreads();

        // ---- normalize + write h ----
#pragma unroll
        for (int lq = 0; lq < 16; lq++) {
            int l = lq * 2 + lp;
            float v = (glu[l][hch] - mean_s[l]) * rstd_s[l] * lw + lb;
            hbuf[hbase + (size_t)l * NH + hch] = v;
        }
        __syncthreads();   // before next tile's ys staging
    }
}

// ---------------- head MLP: one wave per output element ----------------
__global__ void __launch_bounds__(256, 4)
s4w_mlp_wave(const float* __restrict__ in, size_t in_bstride,
             const float* __restrict__ w, const float* __restrict__ bias,
             float* __restrict__ out, int K, int N, int do_relu) {
    int wid = (blockIdx.x * 256 + threadIdx.x) >> 6;
    int lane = threadIdx.x & 63;
    if (wid >= NB * N) return;
    int b = wid / N, o = wid % N;
    const float* ip = in + (size_t)b * in_bstride;
    const float* wp = w + (size_t)o * K;
    float acc = 0.f;
    for (int k = lane; k < K; k += 64) acc = fmaf(wp[k], ip[k], acc);
#pragma unroll
    for (int off = 32; off > 0; off >>= 1) acc += __shfl_xor(acc, off, 64);
    if (lane == 0) {
        float v = acc + bias[o];
        out[(size_t)b * N + o] = do_relu ? fmaxf(v, 0.f) : v;
    }
}

extern "C" void kernel_launch(void* const* d_in, const int* in_sizes, int n_in,
                              void* d_out, int out_size, void* d_ws, size_t ws_size,
                              hipStream_t stream) {
    const float* x          = (const float*)d_in[0];
    const float* enc_w      = (const float*)d_in[1];
    const float* enc_b      = (const float*)d_in[2];
    const float* log_dt     = (const float*)d_in[3];
    const float* C_re       = (const float*)d_in[4];
    const float* C_im       = (const float*)d_in[5];
    const float* log_A_real = (const float*)d_in[6];
    const float* A_imag     = (const float*)d_in[7];
    const float* Dp         = (const float*)d_in[8];
    const float* out_w      = (const float*)d_in[9];
    const float* out_b      = (const float*)d_in[10];
    const float* ln_w       = (const float*)d_in[11];
    const float* ln_b       = (const float*)d_in[12];
    const float* lin1_w     = (const float*)d_in[13];
    const float* lin1_b     = (const float*)d_in[14];
    const float* lin2_w     = (const float*)d_in[15];
    const float* lin2_b     = (const float*)d_in[16];
    const float* lin3_w     = (const float*)d_in[17];
    const float* lin3_b     = (const float*)d_in[18];
    float* outp = (float*)d_out;

    float* ws = (float*)d_ws;
    size_t off = 0;
    float* hbuf = ws + off;              off += (size_t)NB * LSEQ * NH;
    ushort* u_t = (ushort*)(ws + off);   off += (size_t)NH * NBC * 64 / 2;
    ushort* statesbf = (ushort*)(ws + off); off += (size_t)NH * NBC * 64 / 2;
    ushort* wbf = (ushort*)(ws + off);   off += (size_t)NLAY * 2 * NH * NH / 2;
    ushort* Lmat = (ushort*)(ws + off);  off += (size_t)NLAY * NH * 4096 / 2;
    ushort* Wc   = (ushort*)(ws + off);  off += (size_t)NLAY * NH * 4096 / 2;
    ushort* Vmat = (ushort*)(ws + off);  off += (size_t)NLAY * NH * 4096 / 2;
    float* pr_ = ws + off;               off += NLAY * NH * NN;
    float* pi_ = ws + off;               off += NLAY * NH * NN;
    float* t1  = ws + off;               off += NB * ML1;
    float* t2  = ws + off;               off += NB * ML2;
    ushort* ybf = statesbf;   // reuse: states consumed by gemmC before T2 writes ybf

    s4w_coef<<<(NLAY * NH * NN + 255) / 256, 256, 0, stream>>>(
        log_dt, log_A_real, A_imag, pr_, pi_);
    s4w_matprep<<<NLAY * NH, 64, 0, stream>>>(
        log_dt, C_re, C_im, log_A_real, A_imag, Lmat, Wc, Vmat);
    s4w_wprep<<<(NLAY * 2 * NH * NH) / 256, 256, 0, stream>>>(out_w, wbf);

    s4w_enc<<<NB * (LSEQ / 16), 256, 0, stream>>>(x, enc_w, enc_b, hbuf);

    for (int layer = 0; layer < NLAY; layer++) {
        s4w_t1<<<dim3(NBC, 4), 256, 0, stream>>>(hbuf, u_t);
        s4w_gemmA<<<dim3(NH, 4), 256, 0, stream>>>(u_t, Vmat, statesbf, layer);
        s4w_scan<<<(NH * NB * NN) / 256, 256, 0, stream>>>(statesbf, pr_, pi_, layer);
        s4w_gemmC<<<dim3(NH, 4), 256, 0, stream>>>(u_t, statesbf, Lmat, Wc, Dp, layer);
        s4w_t2<<<dim3(NBC, 4), 256, 0, stream>>>(u_t, ybf);
        s4w_proj_mfma<<<dim3(NB, 8), 512, 0, stream>>>(ybf, hbuf, wbf, out_b, ln_w, ln_b, layer);
    }

    s4w_mlp_wave<<<(NB * ML1 + 3) / 4, 256, 0, stream>>>(
        hbuf + (size_t)(LSEQ - 1) * NH, (size_t)LSEQ * NH, lin1_w, lin1_b, t1, NH, ML1, 1);
    s4w_mlp_wave<<<(NB * ML2 + 3) / 4, 256, 0, stream>>>(
        t1, ML1, lin2_w, lin2_b, t2, ML1, ML2, 1);
    s4w_mlp_wave<<<(NB * MOUT + 3) / 4, 256, 0, stream>>>(
        t2, ML2, lin3_w, lin3_b, outp, ML2, MOUT, 0);
}

// Round 14
// 397.472 us; speedup vs baseline: 1.2692x; 1.2105x over previous
//
#include <hip/hip_runtime.h>
#include <hip/hip_bf16.h>
#include <math.h>

#define NB 32
#define LSEQ 2048
#define DIN 64
#define NH 256
#define NN 32
#define NLAY 2
#define NCH 32
#define TCH 64    // LSEQ/NCH
#define NBC (NB*NCH)          // 1024 columns
#define LT 32                 // proj l-tile
#define ML1 350
#define ML2 400
#define MOUT 1024
#define LN_EPS 1e-5f

typedef short short8 __attribute__((ext_vector_type(8)));
typedef short short4v __attribute__((ext_vector_type(4)));
typedef float f32x4 __attribute__((ext_vector_type(4)));

__device__ __forceinline__ float bf2f(ushort u) {
    union { uint i; float f; } v; v.i = ((uint)u) << 16; return v.f;
}
__device__ __forceinline__ ushort f2bf(float f) {
    __hip_bfloat16 h = __float2bfloat16(f);
    return *reinterpret_cast<ushort*>(&h);
}

// ---------------- coefficient prep (E^64 for scan) ----------------
__global__ void s4w_coef(const float* __restrict__ log_dt,
                         const float* __restrict__ log_A_real, const float* __restrict__ A_imag,
                         float* __restrict__ pr_, float* __restrict__ pi_) {
    int idx = blockIdx.x * 256 + threadIdx.x;
    if (idx >= NLAY * NH * NN) return;
    int h = (idx / NN) % NH;
    int l = idx / (NN * NH);
    float dt = expf(log_dt[l * NH + h]);
    float ar = -expf(log_A_real[idx]);
    float ai = A_imag[idx];
    double dre = (double)(ar * dt), dim = (double)(ai * dt);
    double exT = exp(dre * (double)TCH);
    double ang = dim * (double)TCH;
    pr_[idx] = (float)(exT * cos(ang));
    pi_[idx] = (float)(exT * sin(ang));
}

// ---------------- matrix prep: Lmat (causal kernel), Wc (carry), Vmat (end-state) ----------------
__global__ void s4w_matprep(const float* __restrict__ log_dt,
                            const float* __restrict__ C_re, const float* __restrict__ C_im,
                            const float* __restrict__ log_A_real, const float* __restrict__ A_imag,
                            ushort* __restrict__ Lmat, ushort* __restrict__ Wc,
                            ushort* __restrict__ Vmat) {
    int lh = blockIdx.x;          // layer*NH + h
    int t = threadIdx.x;          // 0..63
    __shared__ float ksh[64];
    float dt = expf(log_dt[lh]);
    float kacc = 0.f;
    for (int n = 0; n < NN; n++) {
        int idx = lh * NN + n;
        float ar = -expf(log_A_real[idx]);
        float ai = A_imag[idx];
        float dre = ar * dt, dim = ai * dt;
        float e1 = expf(dre);
        float er1 = e1 * cosf(dim), ei1 = e1 * sinf(dim);
        float den = ar * ar + ai * ai;
        float qr = ((er1 - 1.f) * ar + ei1 * ai) / den;
        float qi = (ei1 * ar - (er1 - 1.f) * ai) / den;
        float cr = C_re[idx], ci = C_im[idx];
        float ctr = 2.f * (cr * qr - ci * qi);
        float cti = 2.f * (cr * qi + ci * qr);
        float ed = expf(dre * (float)t);
        float angd = dim * (float)t;
        float erd = ed * cosf(angd), eid = ed * sinf(angd);
        kacc += ctr * erd - cti * eid;
        float ew = expf(dre * (float)(t + 1));
        float angw = dim * (float)(t + 1);
        float ewr = ew * cosf(angw), ewi = ew * sinf(angw);
        float wr = ctr * ewr - cti * ewi;
        float wi = ctr * ewi + cti * ewr;
        Wc[(size_t)lh * 4096 + t * 64 + 2 * n]     = f2bf(wr);
        Wc[(size_t)lh * 4096 + t * 64 + 2 * n + 1] = f2bf(-wi);
        float ev = expf(dre * (float)(63 - t));
        float angv = dim * (float)(63 - t);
        Vmat[(size_t)lh * 4096 + (2 * n) * 64 + t]     = f2bf(ev * cosf(angv));
        Vmat[(size_t)lh * 4096 + (2 * n + 1) * 64 + t] = f2bf(ev * sinf(angv));
    }
    ksh[t] = kacc;
    __syncthreads();
    for (int j = 0; j < 64; j++)
        Lmat[(size_t)lh * 4096 + t * 64 + j] = (j <= t) ? f2bf(ksh[t - j]) : (ushort)0;
}

// ---------------- weight prep: out_w -> bf16 ----------------
__global__ void s4w_wprep(const float* __restrict__ ow, ushort* __restrict__ wbf) {
    int idx = blockIdx.x * 256 + threadIdx.x;
    wbf[idx] = f2bf(ow[idx]);
}

// ---------------- encoder: writes hbuf f32 AND u_t bf16 (h-major) ----------------
__global__ void __launch_bounds__(256, 2)
s4w_enc(const float* __restrict__ x, const float* __restrict__ w,
        const float* __restrict__ bias, float* __restrict__ hbuf,
        ushort* __restrict__ u_t) {
    int blk = blockIdx.x;
    int b = blk / (LSEQ / 16);
    int l0 = (blk % (LSEQ / 16)) * 16;
    int t = threadIdx.x;
    __shared__ float xs[16][DIN];
    ((float4*)&xs[0][0])[t] = ((const float4*)(x + ((size_t)b * LSEQ + l0) * DIN))[t];
    float wr[DIN];
    const float4* wp4 = (const float4*)(w + (size_t)t * DIN);
#pragma unroll
    for (int i = 0; i < DIN / 4; i++) {
        float4 v = wp4[i];
        wr[4 * i] = v.x; wr[4 * i + 1] = v.y; wr[4 * i + 2] = v.z; wr[4 * i + 3] = v.w;
    }
    float bz = bias[t];
    __syncthreads();
    ushort yb[16];
#pragma unroll 4
    for (int l = 0; l < 16; l++) {
        float acc = bz;
#pragma unroll
        for (int i = 0; i < DIN; i++) acc = fmaf(wr[i], xs[l][i], acc);
        hbuf[((size_t)b * LSEQ + l0 + l) * NH + t] = acc;
        yb[l] = f2bf(acc);
    }
    int c = l0 >> 6, j0 = l0 & 63;
    ushort* ud = u_t + ((size_t)t * NBC + b * NCH + c) * 64 + j0;
    short8 o0, o1;
#pragma unroll
    for (int i = 0; i < 8; i++) { o0[i] = (short)yb[i]; o1[i] = (short)yb[8 + i]; }
    *(short8*)ud = o0;
    *(short8*)(ud + 8) = o1;
}

// ---------------- fused conv: gemmA + scan + gemmC per (h,b), all in LDS ----------------
// block = (h, b), 256 threads / 4 waves. y overwrites u in place.
__global__ void __launch_bounds__(256, 3)
s4w_conv(ushort* __restrict__ u_t,
         const ushort* __restrict__ Lmat, const ushort* __restrict__ Wc,
         const ushort* __restrict__ Vmat,
         const float* __restrict__ pr_, const float* __restrict__ pi_,
         const float* __restrict__ Dp, int layer) {
    int h = blockIdx.x, b = blockIdx.y;
    int t = threadIdx.x;
    int wave = t >> 6, lane = t & 63;
    int lm = lane & 15, kg = lane >> 4;

    __shared__ __align__(16) ushort uS[NCH][72];     // u (then source for epilogue)
    __shared__ __align__(16) ushort lS[64][72];      // Lmat [jout][jin]
    __shared__ __align__(16) ushort wS[64][72];      // Wc   [jout][comp]
    __shared__ __align__(16) ushort vS[64][72];      // Vmat [comp][j]
    __shared__ __align__(16) float  stS[NCH][68];    // end states f32
    __shared__ __align__(16) ushort sbS[NCH][72];    // start states bf16
    __shared__ __align__(16) ushort yS[NCH][72];     // y out

    ushort* ub = u_t + ((size_t)h * NBC + b * NCH) * 64;
    {   // stage u: 2048 ushorts = 32 rows x 64; 256 threads x 8 ushorts
        int r = t >> 3, o = (t & 7) * 8;
        *(short8*)&uS[r][o] = *(const short8*)(ub + r * 64 + o);
    }
    const ushort* Lg = Lmat + (size_t)(layer * NH + h) * 4096;
    const ushort* Wg = Wc   + (size_t)(layer * NH + h) * 4096;
    const ushort* Vg = Vmat + (size_t)(layer * NH + h) * 4096;
#pragma unroll
    for (int p = 0; p < 2; p++) {   // stage matrices: 3 x 8 KB (4096 ushorts each)
        int cid = p * 256 + t;
        int r = cid >> 3, o = (cid & 7) * 8;
        *(short8*)&lS[r][o] = *(const short8*)(Lg + r * 64 + o);
        *(short8*)&wS[r][o] = *(const short8*)(Wg + r * 64 + o);
        *(short8*)&vS[r][o] = *(const short8*)(Vg + r * 64 + o);
    }
    __syncthreads();

    // ---- phase 1: end states = Vmat @ u.  M=comp(64)=4 waves x 16, N=c(32)=2 tiles, K=j(64)
    {
        f32x4 acc[2];
        acc[0] = (f32x4){0.f, 0.f, 0.f, 0.f};
        acc[1] = (f32x4){0.f, 0.f, 0.f, 0.f};
#pragma unroll
        for (int ks = 0; ks < 2; ks++) {
            short8 av = *(const short8*)&vS[wave * 16 + lm][ks * 32 + kg * 8];
#pragma unroll
            for (int nt = 0; nt < 2; nt++) {
                short8 bv = *(const short8*)&uS[nt * 16 + lm][ks * 32 + kg * 8];
                acc[nt] = __builtin_amdgcn_mfma_f32_16x16x32_bf16(av, bv, acc[nt], 0, 0, 0);
            }
        }
#pragma unroll
        for (int nt = 0; nt < 2; nt++) {
            int c = nt * 16 + lm;
            int comp = wave * 16 + kg * 4;
            *(f32x4*)&stS[c][comp] = acc[nt];
        }
    }
    __syncthreads();

    // ---- phase 2: scan end->start states (thread n handles complex state n)
    if (t < NN) {
        float pr = pr_[(size_t)(layer * NH + h) * NN + t];
        float pi = pi_[(size_t)(layer * NH + h) * NN + t];
        float sr = 0.f, si = 0.f;
        for (int c = 0; c < NCH; c++) {
            float er = stS[c][2 * t], ei = stS[c][2 * t + 1];
            sbS[c][2 * t] = f2bf(sr);
            sbS[c][2 * t + 1] = f2bf(si);
            float nsr = pr * sr - pi * si + er;
            float nsi = pr * si + pi * sr + ei;
            sr = nsr; si = nsi;
        }
    }
    __syncthreads();

    // ---- phase 3: Y = Lmat @ u + Wc @ s_start; M=jout 4x16, N=c 2x16, K=64
    f32x4 acc[2];
    acc[0] = (f32x4){0.f, 0.f, 0.f, 0.f};
    acc[1] = (f32x4){0.f, 0.f, 0.f, 0.f};
#pragma unroll
    for (int ks = 0; ks < 2; ks++) {
        short8 avL = *(const short8*)&lS[wave * 16 + lm][ks * 32 + kg * 8];
        short8 avW = *(const short8*)&wS[wave * 16 + lm][ks * 32 + kg * 8];
#pragma unroll
        for (int nt = 0; nt < 2; nt++) {
            short8 bvU = *(const short8*)&uS[nt * 16 + lm][ks * 32 + kg * 8];
            acc[nt] = __builtin_amdgcn_mfma_f32_16x16x32_bf16(avL, bvU, acc[nt], 0, 0, 0);
            short8 bvS = *(const short8*)&sbS[nt * 16 + lm][ks * 32 + kg * 8];
            acc[nt] = __builtin_amdgcn_mfma_f32_16x16x32_bf16(avW, bvS, acc[nt], 0, 0, 0);
        }
    }
    // ---- epilogue: y = acc + Dp*u -> GELU -> yS
    float dp = Dp[layer * NH + h];
#pragma unroll
    for (int nt = 0; nt < 2; nt++) {
        int c = nt * 16 + lm;
        int j0 = wave * 16 + kg * 4;
        short4v uv = *(const short4v*)&uS[c][j0];
        short4v yo;
#pragma unroll
        for (int jj = 0; jj < 4; jj++) {
            float u = bf2f((ushort)uv[jj]);
            float y = acc[nt][jj] + dp * u;
            float g = 0.5f * y * (1.0f + erff(y * 0.70710678118f));
            yo[jj] = (short)f2bf(g);
        }
        *(short4v*)&yS[c][j0] = yo;
    }
    __syncthreads();
    {   // flush y: 2048 ushorts coalesced, in place over u
        int r = t >> 3, o = (t & 7) * 8;
        *(short8*)(ub + r * 64 + o) = *(const short8*)&yS[r][o];
    }
}

// ---------------- T2: y_t bf16 [h][bc][j] -> ybf bf16 [b][l][h] ----------------
__global__ void __launch_bounds__(256, 2)
s4w_t2(const ushort* __restrict__ y_t, ushort* __restrict__ ybf) {
    int bc = blockIdx.x;
    int ht = blockIdx.y;
    int b = bc >> 5, c = bc & 31;
    int t = threadIdx.x;
    __shared__ ushort tile[64][65];   // [h'][j]
    int hr = t >> 2, jq = t & 3;
    const ushort* src = y_t + ((size_t)(ht * 64 + hr) * NBC + bc) * 64 + jq * 16;
    short8 i0 = *(const short8*)src;
    short8 i1 = *(const short8*)(src + 8);
#pragma unroll
    for (int i = 0; i < 8; i++) {
        tile[hr][jq * 16 + i] = (ushort)i0[i];
        tile[hr][jq * 16 + 8 + i] = (ushort)i1[i];
    }
    __syncthreads();
    int jr = t >> 2, hq = t & 3;
    ushort* dst = ybf + ((size_t)(b * LSEQ + c * 64 + jr)) * NH + ht * 64 + hq * 16;
    short8 o0, o1;
#pragma unroll
    for (int i = 0; i < 8; i++) {
        o0[i] = (short)tile[hq * 16 + i][jr];
        o1[i] = (short)tile[hq * 16 + 8 + i][jr];
    }
    *(short8*)dst = o0;
    *(short8*)(dst + 8) = o1;
}

// ---------------- proj v4: 8 waves, register-resident W, writes next-layer u_t ----------------
__global__ void __launch_bounds__(512, 2)
s4w_proj_mfma(const ushort* __restrict__ ybf, float* __restrict__ hbuf,
              const ushort* __restrict__ wbf, const float* __restrict__ ob,
              const float* __restrict__ lnw, const float* __restrict__ lnb,
              ushort* __restrict__ u_t, int write_u, int layer) {
    int b = blockIdx.x;
    int chunk = blockIdx.y;            // 8 chunks of 256 l
    int t = threadIdx.x;
    int wave = t >> 6, lane = t & 63;
    int lm = lane & 15, kg = lane >> 4;

    __shared__ __align__(16) char sbuf[LT * (NH + 1) * 4];   // ys/glu alias
    typedef ushort ysrow[NH + 8];
    typedef float glurow[NH + 1];
    ysrow* ys = (ysrow*)sbuf;
    glurow* glu = (glurow*)sbuf;
    __shared__ float ps[512], pq[512];
    __shared__ float mean_s[LT], rstd_s[LT];

    const ushort* wp = wbf + (size_t)layer * 512 * NH;

    short8 av[4][8];
#pragma unroll
    for (int mi = 0; mi < 4; mi++) {
        int o = (mi < 2 ? wave * 32 + mi * 16 : 256 + wave * 32 + (mi - 2) * 16) + lm;
#pragma unroll
        for (int ks = 0; ks < 8; ks++)
            av[mi][ks] = *(const short8*)(wp + (size_t)o * NH + ks * 32 + kg * 8);
    }

    float oba[2][4], obg[2][4];
#pragma unroll
    for (int mi = 0; mi < 2; mi++)
#pragma unroll
        for (int j = 0; j < 4; j++) {
            int o = wave * 32 + mi * 16 + kg * 4 + j;
            oba[mi][j] = ob[layer * 2 * NH + o];
            obg[mi][j] = ob[layer * 2 * NH + NH + o];
        }
    int hch = t & 255, lp = t >> 8;
    float lw = lnw[layer * NH + hch], lb = lnb[layer * NH + hch];

    for (int tile = 0; tile < 8; tile++) {
        int l0 = chunk * 256 + tile * LT;
        const size_t hbase = ((size_t)b * LSEQ + l0) * NH;

        const ushort* ysrc = ybf + ((size_t)b * LSEQ + l0) * NH;
#pragma unroll
        for (int p = 0; p < 2; p++) {
            int cid = p * 512 + t;
            int row = cid >> 5, ch = cid & 31;
            *(short8*)&ys[row][ch * 8] = *(const short8*)(ysrc + (size_t)row * NH + ch * 8);
        }
        __syncthreads();

        f32x4 acc[4][2];
#pragma unroll
        for (int i = 0; i < 4; i++)
#pragma unroll
            for (int j = 0; j < 2; j++) acc[i][j] = (f32x4){0.f, 0.f, 0.f, 0.f};

#pragma unroll
        for (int ks = 0; ks < 8; ks++) {
            short8 bv[2];
#pragma unroll
            for (int ni = 0; ni < 2; ni++)
                bv[ni] = *(const short8*)&ys[ni * 16 + lm][ks * 32 + kg * 8];
#pragma unroll
            for (int mi = 0; mi < 4; mi++)
#pragma unroll
                for (int ni = 0; ni < 2; ni++)
                    acc[mi][ni] = __builtin_amdgcn_mfma_f32_16x16x32_bf16(av[mi][ks], bv[ni], acc[mi][ni], 0, 0, 0);
        }
        __syncthreads();

#pragma unroll
        for (int mi = 0; mi < 2; mi++)
#pragma unroll
            for (int ni = 0; ni < 2; ni++)
#pragma unroll
                for (int j = 0; j < 4; j++) {
                    float a = acc[mi][ni][j] + oba[mi][j];
                    float g = acc[mi + 2][ni][j] + obg[mi][j];
                    float v = a * (1.0f / (1.0f + expf(-g)));
                    glu[ni * 16 + lm][wave * 32 + mi * 16 + kg * 4 + j] = v;
                }
        __syncthreads();

#pragma unroll
        for (int lq = 0; lq < 16; lq++) {
            int l = lp * 16 + lq;
            glu[l][hch] += hbuf[hbase + (size_t)l * NH + hch];
        }
        __syncthreads();

        {
            int l = t & 31, seg = t >> 5;
            float s = 0.f, q = 0.f;
#pragma unroll
            for (int i = 0; i < 16; i++) {
                float v = glu[l][seg * 16 + i];
                s += v; q = fmaf(v, v, q);
            }
            ps[t] = s; pq[t] = q;
        }
        __syncthreads();
        if (t < LT) {
            float S = 0.f, Q = 0.f;
#pragma unroll
            for (int k = 0; k < 16; k++) { S += ps[k * 32 + t]; Q += pq[k * 32 + t]; }
            float m = S * (1.0f / NH);
            float v = Q * (1.0f / NH) - m * m;
            mean_s[t] = m; rstd_s[t] = rsqrtf(v + LN_EPS);
        }
        __syncthreads();

        ushort yb16[16];
#pragma unroll
        for (int lq = 0; lq < 16; lq++) {
            int l = lp * 16 + lq;
            float v = (glu[l][hch] - mean_s[l]) * rstd_s[l] * lw + lb;
            hbuf[hbase + (size_t)l * NH + hch] = v;
            yb16[lq] = f2bf(v);
        }
        if (write_u) {
            int lg0 = l0 + lp * 16;
            int c = lg0 >> 6, j0 = lg0 & 63;
            ushort* ud = u_t + ((size_t)hch * NBC + b * NCH + c) * 64 + j0;
            short8 o0, o1;
#pragma unroll
            for (int i = 0; i < 8; i++) { o0[i] = (short)yb16[i]; o1[i] = (short)yb16[8 + i]; }
            *(short8*)ud = o0;
            *(short8*)(ud + 8) = o1;
        }
        __syncthreads();
    }
}

// ---------------- head MLP: one wave per output element ----------------
__global__ void __launch_bounds__(256, 4)
s4w_mlp_wave(const float* __restrict__ in, size_t in_bstride,
             const float* __restrict__ w, const float* __restrict__ bias,
             float* __restrict__ out, int K, int N, int do_relu) {
    int wid = (blockIdx.x * 256 + threadIdx.x) >> 6;
    int lane = threadIdx.x & 63;
    if (wid >= NB * N) return;
    int b = wid / N, o = wid % N;
    const float* ip = in + (size_t)b * in_bstride;
    const float* wp = w + (size_t)o * K;
    float acc = 0.f;
    for (int k = lane; k < K; k += 64) acc = fmaf(wp[k], ip[k], acc);
#pragma unroll
    for (int off = 32; off > 0; off >>= 1) acc += __shfl_xor(acc, off, 64);
    if (lane == 0) {
        float v = acc + bias[o];
        out[(size_t)b * N + o] = do_relu ? fmaxf(v, 0.f) : v;
    }
}

extern "C" void kernel_launch(void* const* d_in, const int* in_sizes, int n_in,
                              void* d_out, int out_size, void* d_ws, size_t ws_size,
                              hipStream_t stream) {
    const float* x          = (const float*)d_in[0];
    const float* enc_w      = (const float*)d_in[1];
    const float* enc_b      = (const float*)d_in[2];
    const float* log_dt     = (const float*)d_in[3];
    const float* C_re       = (const float*)d_in[4];
    const float* C_im       = (const float*)d_in[5];
    const float* log_A_real = (const float*)d_in[6];
    const float* A_imag     = (const float*)d_in[7];
    const float* Dp         = (const float*)d_in[8];
    const float* out_w      = (const float*)d_in[9];
    const float* out_b      = (const float*)d_in[10];
    const float* ln_w       = (const float*)d_in[11];
    const float* ln_b       = (const float*)d_in[12];
    const float* lin1_w     = (const float*)d_in[13];
    const float* lin1_b     = (const float*)d_in[14];
    const float* lin2_w     = (const float*)d_in[15];
    const float* lin2_b     = (const float*)d_in[16];
    const float* lin3_w     = (const float*)d_in[17];
    const float* lin3_b     = (const float*)d_in[18];
    float* outp = (float*)d_out;

    float* ws = (float*)d_ws;
    size_t off = 0;
    float* hbuf = ws + off;              off += (size_t)NB * LSEQ * NH;
    ushort* u_t = (ushort*)(ws + off);   off += (size_t)NH * NBC * 64 / 2;
    ushort* ybf = (ushort*)(ws + off);   off += (size_t)NB * LSEQ * NH / 2;
    ushort* wbf = (ushort*)(ws + off);   off += (size_t)NLAY * 2 * NH * NH / 2;
    ushort* Lmat = (ushort*)(ws + off);  off += (size_t)NLAY * NH * 4096 / 2;
    ushort* Wc   = (ushort*)(ws + off);  off += (size_t)NLAY * NH * 4096 / 2;
    ushort* Vmat = (ushort*)(ws + off);  off += (size_t)NLAY * NH * 4096 / 2;
    float* pr_ = ws + off;               off += NLAY * NH * NN;
    float* pi_ = ws + off;               off += NLAY * NH * NN;
    float* t1  = ws + off;               off += NB * ML1;
    float* t2  = ws + off;               off += NB * ML2;

    s4w_coef<<<(NLAY * NH * NN + 255) / 256, 256, 0, stream>>>(
        log_dt, log_A_real, A_imag, pr_, pi_);
    s4w_matprep<<<NLAY * NH, 64, 0, stream>>>(
        log_dt, C_re, C_im, log_A_real, A_imag, Lmat, Wc, Vmat);
    s4w_wprep<<<(NLAY * 2 * NH * NH) / 256, 256, 0, stream>>>(out_w, wbf);

    s4w_enc<<<NB * (LSEQ / 16), 256, 0, stream>>>(x, enc_w, enc_b, hbuf, u_t);

    for (int layer = 0; layer < NLAY; layer++) {
        s4w_conv<<<dim3(NH, NB), 256, 0, stream>>>(u_t, Lmat, Wc, Vmat, pr_, pi_, Dp, layer);
        s4w_t2<<<dim3(NBC, 4), 256, 0, stream>>>(u_t, ybf);
        s4w_proj_mfma<<<dim3(NB, 8), 512, 0, stream>>>(
            ybf, hbuf, wbf, out_b, ln_w, ln_b, u_t, layer < NLAY - 1 ? 1 : 0, layer);
    }

    s4w_mlp_wave<<<(NB * ML1 + 3) / 4, 256, 0, stream>>>(
        hbuf + (size_t)(LSEQ - 1) * NH, (size_t)LSEQ * NH, lin1_w, lin1_b, t1, NH, ML1, 1);
    s4w_mlp_wave<<<(NB * ML2 + 3) / 4, 256, 0, stream>>>(
        t1, ML1, lin2_w, lin2_b, t2, ML1, ML2, 1);
    s4w_mlp_wave<<<(NB * MOUT + 3) / 4, 256, 0, stream>>>(
        t2, ML2, lin3_w, lin3_b, outp, ML2, MOUT, 0);
}

// Round 15
// 324.010 us; speedup vs baseline: 1.5569x; 1.2267x over previous
//
#include <hip/hip_runtime.h>
#include <hip/hip_bf16.h>
#include <math.h>

#define NB 32
#define LSEQ 2048
#define DIN 64
#define NH 256
#define NN 32
#define NLAY 2
#define NCH 32
#define TCH 64    // LSEQ/NCH
#define NBC (NB*NCH)          // 1024 columns
#define LT 32                 // proj l-tile
#define ML1 350
#define ML2 400
#define MOUT 1024
#define LN_EPS 1e-5f

typedef short short8 __attribute__((ext_vector_type(8)));
typedef short short4v __attribute__((ext_vector_type(4)));
typedef float f32x4 __attribute__((ext_vector_type(4)));

__device__ __forceinline__ float bf2f(ushort u) {
    union { uint i; float f; } v; v.i = ((uint)u) << 16; return v.f;
}
__device__ __forceinline__ ushort f2bf(float f) {
    __hip_bfloat16 h = __float2bfloat16(f);
    return *reinterpret_cast<ushort*>(&h);
}

// ---------------- coefficient prep (E^64 for scan) ----------------
__global__ void s4w_coef(const float* __restrict__ log_dt,
                         const float* __restrict__ log_A_real, const float* __restrict__ A_imag,
                         float* __restrict__ pr_, float* __restrict__ pi_) {
    int idx = blockIdx.x * 256 + threadIdx.x;
    if (idx >= NLAY * NH * NN) return;
    int h = (idx / NN) % NH;
    int l = idx / (NN * NH);
    float dt = expf(log_dt[l * NH + h]);
    float ar = -expf(log_A_real[idx]);
    float ai = A_imag[idx];
    double dre = (double)(ar * dt), dim = (double)(ai * dt);
    double exT = exp(dre * (double)TCH);
    double ang = dim * (double)TCH;
    pr_[idx] = (float)(exT * cos(ang));
    pi_[idx] = (float)(exT * sin(ang));
}

// ---------------- matrix prep: Lmat (causal kernel), Wc (carry), Vmat (end-state) ----------------
__global__ void s4w_matprep(const float* __restrict__ log_dt,
                            const float* __restrict__ C_re, const float* __restrict__ C_im,
                            const float* __restrict__ log_A_real, const float* __restrict__ A_imag,
                            ushort* __restrict__ Lmat, ushort* __restrict__ Wc,
                            ushort* __restrict__ Vmat) {
    int lh = blockIdx.x;          // layer*NH + h
    int t = threadIdx.x;          // 0..63
    __shared__ float ksh[64];
    float dt = expf(log_dt[lh]);
    float kacc = 0.f;
    for (int n = 0; n < NN; n++) {
        int idx = lh * NN + n;
        float ar = -expf(log_A_real[idx]);
        float ai = A_imag[idx];
        float dre = ar * dt, dim = ai * dt;
        float e1 = expf(dre);
        float er1 = e1 * cosf(dim), ei1 = e1 * sinf(dim);
        float den = ar * ar + ai * ai;
        float qr = ((er1 - 1.f) * ar + ei1 * ai) / den;
        float qi = (ei1 * ar - (er1 - 1.f) * ai) / den;
        float cr = C_re[idx], ci = C_im[idx];
        float ctr = 2.f * (cr * qr - ci * qi);
        float cti = 2.f * (cr * qi + ci * qr);
        float ed = expf(dre * (float)t);
        float angd = dim * (float)t;
        float erd = ed * cosf(angd), eid = ed * sinf(angd);
        kacc += ctr * erd - cti * eid;
        float ew = expf(dre * (float)(t + 1));
        float angw = dim * (float)(t + 1);
        float ewr = ew * cosf(angw), ewi = ew * sinf(angw);
        float wr = ctr * ewr - cti * ewi;
        float wi = ctr * ewi + cti * ewr;
        Wc[(size_t)lh * 4096 + t * 64 + 2 * n]     = f2bf(wr);
        Wc[(size_t)lh * 4096 + t * 64 + 2 * n + 1] = f2bf(-wi);
        float ev = expf(dre * (float)(63 - t));
        float angv = dim * (float)(63 - t);
        Vmat[(size_t)lh * 4096 + (2 * n) * 64 + t]     = f2bf(ev * cosf(angv));
        Vmat[(size_t)lh * 4096 + (2 * n + 1) * 64 + t] = f2bf(ev * sinf(angv));
    }
    ksh[t] = kacc;
    __syncthreads();
    for (int j = 0; j < 64; j++)
        Lmat[(size_t)lh * 4096 + t * 64 + j] = (j <= t) ? f2bf(ksh[t - j]) : (ushort)0;
}

// ---------------- weight prep: out_w -> bf16 ----------------
__global__ void s4w_wprep(const float* __restrict__ ow, ushort* __restrict__ wbf) {
    int idx = blockIdx.x * 256 + threadIdx.x;
    wbf[idx] = f2bf(ow[idx]);
}

// ---------------- encoder: writes hbf bf16 AND u_t bf16 (h-major) ----------------
__global__ void __launch_bounds__(256, 2)
s4w_enc(const float* __restrict__ x, const float* __restrict__ w,
        const float* __restrict__ bias, ushort* __restrict__ hbf,
        ushort* __restrict__ u_t) {
    int blk = blockIdx.x;
    int b = blk / (LSEQ / 16);
    int l0 = (blk % (LSEQ / 16)) * 16;
    int t = threadIdx.x;
    __shared__ float xs[16][DIN];
    ((float4*)&xs[0][0])[t] = ((const float4*)(x + ((size_t)b * LSEQ + l0) * DIN))[t];
    float wr[DIN];
    const float4* wp4 = (const float4*)(w + (size_t)t * DIN);
#pragma unroll
    for (int i = 0; i < DIN / 4; i++) {
        float4 v = wp4[i];
        wr[4 * i] = v.x; wr[4 * i + 1] = v.y; wr[4 * i + 2] = v.z; wr[4 * i + 3] = v.w;
    }
    float bz = bias[t];
    __syncthreads();
    ushort yb[16];
#pragma unroll 4
    for (int l = 0; l < 16; l++) {
        float acc = bz;
#pragma unroll
        for (int i = 0; i < DIN; i++) acc = fmaf(wr[i], xs[l][i], acc);
        yb[l] = f2bf(acc);
        hbf[((size_t)b * LSEQ + l0 + l) * NH + t] = yb[l];
    }
    int c = l0 >> 6, j0 = l0 & 63;
    ushort* ud = u_t + ((size_t)t * NBC + b * NCH + c) * 64 + j0;
    short8 o0, o1;
#pragma unroll
    for (int i = 0; i < 8; i++) { o0[i] = (short)yb[i]; o1[i] = (short)yb[8 + i]; }
    *(short8*)ud = o0;
    *(short8*)(ud + 8) = o1;
}

// ---------------- fused conv: gemmA + scan + gemmC; block = (h, 4 b's), in LDS ----------------
__global__ void __launch_bounds__(256, 3)
s4w_conv(ushort* __restrict__ u_t,
         const ushort* __restrict__ Lmat, const ushort* __restrict__ Wc,
         const ushort* __restrict__ Vmat,
         const float* __restrict__ pr_, const float* __restrict__ pi_,
         const float* __restrict__ Dp, int layer) {
    int h = blockIdx.x, bq = blockIdx.y;
    int t = threadIdx.x;
    int wave = t >> 6, lane = t & 63;
    int lm = lane & 15, kg = lane >> 4;

    __shared__ __align__(16) ushort uS[NCH][72];
    __shared__ __align__(16) ushort lS[64][72];
    __shared__ __align__(16) ushort wS[64][72];
    __shared__ __align__(16) ushort vS[64][72];
    __shared__ __align__(16) float  stS[NCH][68];
    __shared__ __align__(16) ushort sbS[NCH][72];
    __shared__ __align__(16) ushort yS[NCH][72];

    const ushort* Lg = Lmat + (size_t)(layer * NH + h) * 4096;
    const ushort* Wg = Wc   + (size_t)(layer * NH + h) * 4096;
    const ushort* Vg = Vmat + (size_t)(layer * NH + h) * 4096;
#pragma unroll
    for (int p = 0; p < 2; p++) {   // stage matrices once: 3 x 8 KB
        int cid = p * 256 + t;
        int r = cid >> 3, o = (cid & 7) * 8;
        *(short8*)&lS[r][o] = *(const short8*)(Lg + r * 64 + o);
        *(short8*)&wS[r][o] = *(const short8*)(Wg + r * 64 + o);
        *(short8*)&vS[r][o] = *(const short8*)(Vg + r * 64 + o);
    }
    float dp = Dp[layer * NH + h];
    float prv = 0.f, piv = 0.f;
    if (t < NN) {
        prv = pr_[(size_t)(layer * NH + h) * NN + t];
        piv = pi_[(size_t)(layer * NH + h) * NN + t];
    }

    for (int bi = 0; bi < 4; bi++) {
        int b = bq * 4 + bi;
        ushort* ub = u_t + ((size_t)h * NBC + b * NCH) * 64;
        {   // stage u: 2048 ushorts = 32 rows x 64
            int r = t >> 3, o = (t & 7) * 8;
            *(short8*)&uS[r][o] = *(const short8*)(ub + r * 64 + o);
        }
        __syncthreads();

        // phase 1: end states = Vmat @ u
        {
            f32x4 acc[2];
            acc[0] = (f32x4){0.f, 0.f, 0.f, 0.f};
            acc[1] = (f32x4){0.f, 0.f, 0.f, 0.f};
#pragma unroll
            for (int ks = 0; ks < 2; ks++) {
                short8 av = *(const short8*)&vS[wave * 16 + lm][ks * 32 + kg * 8];
#pragma unroll
                for (int nt = 0; nt < 2; nt++) {
                    short8 bv = *(const short8*)&uS[nt * 16 + lm][ks * 32 + kg * 8];
                    acc[nt] = __builtin_amdgcn_mfma_f32_16x16x32_bf16(av, bv, acc[nt], 0, 0, 0);
                }
            }
#pragma unroll
            for (int nt = 0; nt < 2; nt++) {
                int c = nt * 16 + lm;
                int comp = wave * 16 + kg * 4;
                *(f32x4*)&stS[c][comp] = acc[nt];
            }
        }
        __syncthreads();

        // phase 2: scan end->start states
        if (t < NN) {
            float sr = 0.f, si = 0.f;
            for (int c = 0; c < NCH; c++) {
                float er = stS[c][2 * t], ei = stS[c][2 * t + 1];
                sbS[c][2 * t] = f2bf(sr);
                sbS[c][2 * t + 1] = f2bf(si);
                float nsr = prv * sr - piv * si + er;
                float nsi = prv * si + piv * sr + ei;
                sr = nsr; si = nsi;
            }
        }
        __syncthreads();

        // phase 3: Y = Lmat @ u + Wc @ s_start
        f32x4 acc[2];
        acc[0] = (f32x4){0.f, 0.f, 0.f, 0.f};
        acc[1] = (f32x4){0.f, 0.f, 0.f, 0.f};
#pragma unroll
        for (int ks = 0; ks < 2; ks++) {
            short8 avL = *(const short8*)&lS[wave * 16 + lm][ks * 32 + kg * 8];
            short8 avW = *(const short8*)&wS[wave * 16 + lm][ks * 32 + kg * 8];
#pragma unroll
            for (int nt = 0; nt < 2; nt++) {
                short8 bvU = *(const short8*)&uS[nt * 16 + lm][ks * 32 + kg * 8];
                acc[nt] = __builtin_amdgcn_mfma_f32_16x16x32_bf16(avL, bvU, acc[nt], 0, 0, 0);
                short8 bvS = *(const short8*)&sbS[nt * 16 + lm][ks * 32 + kg * 8];
                acc[nt] = __builtin_amdgcn_mfma_f32_16x16x32_bf16(avW, bvS, acc[nt], 0, 0, 0);
            }
        }
        // epilogue: y = acc + Dp*u -> GELU -> yS
#pragma unroll
        for (int nt = 0; nt < 2; nt++) {
            int c = nt * 16 + lm;
            int j0 = wave * 16 + kg * 4;
            short4v uv = *(const short4v*)&uS[c][j0];
            short4v yo;
#pragma unroll
            for (int jj = 0; jj < 4; jj++) {
                float u = bf2f((ushort)uv[jj]);
                float y = acc[nt][jj] + dp * u;
                float g = 0.5f * y * (1.0f + erff(y * 0.70710678118f));
                yo[jj] = (short)f2bf(g);
            }
            *(short4v*)&yS[c][j0] = yo;
        }
        __syncthreads();
        {   // flush y in place over u
            int r = t >> 3, o = (t & 7) * 8;
            *(short8*)(ub + r * 64 + o) = *(const short8*)&yS[r][o];
        }
        __syncthreads();
    }
}

// ---------------- proj v5: stages from u_t (transpose), pipelined, bf16 h ----------------
__global__ void __launch_bounds__(512, 2)
s4w_proj_mfma(ushort* __restrict__ u_t, ushort* __restrict__ hbf,
              const ushort* __restrict__ wbf, const float* __restrict__ ob,
              const float* __restrict__ lnw, const float* __restrict__ lnb,
              int write_u, int layer) {
    int b = blockIdx.x;
    int chunk = blockIdx.y;            // 8 chunks of 256 l
    int t = threadIdx.x;
    int wave = t >> 6, lane = t & 63;
    int lm = lane & 15, kg = lane >> 4;
    int hch = t & 255, lp = t >> 8;    // staging/epilogue mapping

    __shared__ __align__(16) char sbuf[LT * (NH + 1) * 4];   // ys/glu alias
    typedef ushort ysrow[NH + 8];
    typedef float glurow[NH + 1];
    ysrow* ys = (ysrow*)sbuf;
    glurow* glu = (glurow*)sbuf;
    __shared__ float ps[512], pq[512];
    __shared__ float mean_s[LT], rstd_s[LT];

    const ushort* wp = wbf + (size_t)layer * 512 * NH;

    short8 av[4][8];
#pragma unroll
    for (int mi = 0; mi < 4; mi++) {
        int o = (mi < 2 ? wave * 32 + mi * 16 : 256 + wave * 32 + (mi - 2) * 16) + lm;
#pragma unroll
        for (int ks = 0; ks < 8; ks++)
            av[mi][ks] = *(const short8*)(wp + (size_t)o * NH + ks * 32 + kg * 8);
    }

    float oba[2][4], obg[2][4];
#pragma unroll
    for (int mi = 0; mi < 2; mi++)
#pragma unroll
        for (int j = 0; j < 4; j++) {
            int o = wave * 32 + mi * 16 + kg * 4 + j;
            oba[mi][j] = ob[layer * 2 * NH + o];
            obg[mi][j] = ob[layer * 2 * NH + NH + o];
        }
    float lw = lnw[layer * NH + hch], lb = lnb[layer * NH + hch];

    // prefetch tile 0 ys regs
    short8 pre0, pre1;
    {
        int l0 = chunk * 256;
        int c = l0 >> 6, j0 = l0 & 63;
        const ushort* src = u_t + ((size_t)hch * NBC + b * NCH + c) * 64 + j0 + lp * 16;
        pre0 = *(const short8*)src;
        pre1 = *(const short8*)(src + 8);
    }

    for (int tile = 0; tile < 8; tile++) {
        int l0 = chunk * 256 + tile * LT;
        const size_t hbase = ((size_t)b * LSEQ + l0) * NH;

        // write prefetched ys regs -> LDS transpose: ys[li][hch]
        {
            int li0 = lp * 16;
#pragma unroll
            for (int i = 0; i < 8; i++) ys[li0 + i][hch] = (ushort)pre0[i];
#pragma unroll
            for (int i = 0; i < 8; i++) ys[li0 + 8 + i][hch] = (ushort)pre1[i];
        }
        // issue this tile's residual loads into regs
        ushort res[16];
#pragma unroll
        for (int lq = 0; lq < 16; lq++)
            res[lq] = hbf[hbase + (size_t)(lp * 16 + lq) * NH + hch];
        // issue next tile's ys loads
        if (tile < 7) {
            int l0n = l0 + LT;
            int c = l0n >> 6, j0 = l0n & 63;
            const ushort* src = u_t + ((size_t)hch * NBC + b * NCH + c) * 64 + j0 + lp * 16;
            pre0 = *(const short8*)src;
            pre1 = *(const short8*)(src + 8);
        }
        __syncthreads();

        f32x4 acc[4][2];
#pragma unroll
        for (int i = 0; i < 4; i++)
#pragma unroll
            for (int j = 0; j < 2; j++) acc[i][j] = (f32x4){0.f, 0.f, 0.f, 0.f};

#pragma unroll
        for (int ks = 0; ks < 8; ks++) {
            short8 bv[2];
#pragma unroll
            for (int ni = 0; ni < 2; ni++)
                bv[ni] = *(const short8*)&ys[ni * 16 + lm][ks * 32 + kg * 8];
#pragma unroll
            for (int mi = 0; mi < 4; mi++)
#pragma unroll
                for (int ni = 0; ni < 2; ni++)
                    acc[mi][ni] = __builtin_amdgcn_mfma_f32_16x16x32_bf16(av[mi][ks], bv[ni], acc[mi][ni], 0, 0, 0);
        }
        __syncthreads();   // ys reads done before glu overwrite

        // bias + GLU -> glu
#pragma unroll
        for (int mi = 0; mi < 2; mi++)
#pragma unroll
            for (int ni = 0; ni < 2; ni++)
#pragma unroll
                for (int j = 0; j < 4; j++) {
                    float a = acc[mi][ni][j] + oba[mi][j];
                    float g = acc[mi + 2][ni][j] + obg[mi][j];
                    float v = a * (1.0f / (1.0f + expf(-g)));
                    glu[ni * 16 + lm][wave * 32 + mi * 16 + kg * 4 + j] = v;
                }
        __syncthreads();

        // residual add from regs
#pragma unroll
        for (int lq = 0; lq < 16; lq++)
            glu[lp * 16 + lq][hch] += bf2f(res[lq]);
        __syncthreads();

        // LN stats
        {
            int l = t & 31, seg = t >> 5;
            float s = 0.f, q = 0.f;
#pragma unroll
            for (int i = 0; i < 16; i++) {
                float v = glu[l][seg * 16 + i];
                s += v; q = fmaf(v, v, q);
            }
            ps[t] = s; pq[t] = q;
        }
        __syncthreads();
        if (t < LT) {
            float S = 0.f, Q = 0.f;
#pragma unroll
            for (int k = 0; k < 16; k++) { S += ps[k * 32 + t]; Q += pq[k * 32 + t]; }
            float m = S * (1.0f / NH);
            float v = Q * (1.0f / NH) - m * m;
            mean_s[t] = m; rstd_s[t] = rsqrtf(v + LN_EPS);
        }
        __syncthreads();

        ushort yb16[16];
#pragma unroll
        for (int lq = 0; lq < 16; lq++) {
            int l = lp * 16 + lq;
            float v = (glu[l][hch] - mean_s[l]) * rstd_s[l] * lw + lb;
            yb16[lq] = f2bf(v);
            hbf[hbase + (size_t)l * NH + hch] = yb16[lq];
        }
        if (write_u) {
            int lg0 = l0 + lp * 16;
            int c = lg0 >> 6, j0 = lg0 & 63;
            ushort* ud = u_t + ((size_t)hch * NBC + b * NCH + c) * 64 + j0;
            short8 o0, o1;
#pragma unroll
            for (int i = 0; i < 8; i++) { o0[i] = (short)yb16[i]; o1[i] = (short)yb16[8 + i]; }
            *(short8*)ud = o0;
            *(short8*)(ud + 8) = o1;
        }
        __syncthreads();   // glu reads done before next tile's ys write
    }
}

// ---------------- head MLP: one wave per output element ----------------
__global__ void __launch_bounds__(256, 4)
s4w_mlp_wave(const void* __restrict__ in, size_t in_bstride,
             const float* __restrict__ w, const float* __restrict__ bias,
             float* __restrict__ out, int K, int N, int do_relu, int in_bf16) {
    int wid = (blockIdx.x * 256 + threadIdx.x) >> 6;
    int lane = threadIdx.x & 63;
    if (wid >= NB * N) return;
    int b = wid / N, o = wid % N;
    const float* wp = w + (size_t)o * K;
    float acc = 0.f;
    if (in_bf16) {
        const ushort* ip = (const ushort*)in + (size_t)b * in_bstride;
        for (int k = lane; k < K; k += 64) acc = fmaf(wp[k], bf2f(ip[k]), acc);
    } else {
        const float* ip = (const float*)in + (size_t)b * in_bstride;
        for (int k = lane; k < K; k += 64) acc = fmaf(wp[k], ip[k], acc);
    }
#pragma unroll
    for (int off = 32; off > 0; off >>= 1) acc += __shfl_xor(acc, off, 64);
    if (lane == 0) {
        float v = acc + bias[o];
        out[(size_t)b * N + o] = do_relu ? fmaxf(v, 0.f) : v;
    }
}

extern "C" void kernel_launch(void* const* d_in, const int* in_sizes, int n_in,
                              void* d_out, int out_size, void* d_ws, size_t ws_size,
                              hipStream_t stream) {
    const float* x          = (const float*)d_in[0];
    const float* enc_w      = (const float*)d_in[1];
    const float* enc_b      = (const float*)d_in[2];
    const float* log_dt     = (const float*)d_in[3];
    const float* C_re       = (const float*)d_in[4];
    const float* C_im       = (const float*)d_in[5];
    const float* log_A_real = (const float*)d_in[6];
    const float* A_imag     = (const float*)d_in[7];
    const float* Dp         = (const float*)d_in[8];
    const float* out_w      = (const float*)d_in[9];
    const float* out_b      = (const float*)d_in[10];
    const float* ln_w       = (const float*)d_in[11];
    const float* ln_b       = (const float*)d_in[12];
    const float* lin1_w     = (const float*)d_in[13];
    const float* lin1_b     = (const float*)d_in[14];
    const float* lin2_w     = (const float*)d_in[15];
    const float* lin2_b     = (const float*)d_in[16];
    const float* lin3_w     = (const float*)d_in[17];
    const float* lin3_b     = (const float*)d_in[18];
    float* outp = (float*)d_out;

    float* ws = (float*)d_ws;
    size_t off = 0;
    ushort* hbf = (ushort*)(ws + off);   off += (size_t)NB * LSEQ * NH / 2;
    ushort* u_t = (ushort*)(ws + off);   off += (size_t)NB * LSEQ * NH / 2;
    ushort* wbf = (ushort*)(ws + off);   off += (size_t)NLAY * 2 * NH * NH / 2;
    ushort* Lmat = (ushort*)(ws + off);  off += (size_t)NLAY * NH * 4096 / 2;
    ushort* Wc   = (ushort*)(ws + off);  off += (size_t)NLAY * NH * 4096 / 2;
    ushort* Vmat = (ushort*)(ws + off);  off += (size_t)NLAY * NH * 4096 / 2;
    float* pr_ = ws + off;               off += NLAY * NH * NN;
    float* pi_ = ws + off;               off += NLAY * NH * NN;
    float* t1  = ws + off;               off += NB * ML1;
    float* t2  = ws + off;               off += NB * ML2;

    s4w_coef<<<(NLAY * NH * NN + 255) / 256, 256, 0, stream>>>(
        log_dt, log_A_real, A_imag, pr_, pi_);
    s4w_matprep<<<NLAY * NH, 64, 0, stream>>>(
        log_dt, C_re, C_im, log_A_real, A_imag, Lmat, Wc, Vmat);
    s4w_wprep<<<(NLAY * 2 * NH * NH) / 256, 256, 0, stream>>>(out_w, wbf);

    s4w_enc<<<NB * (LSEQ / 16), 256, 0, stream>>>(x, enc_w, enc_b, hbf, u_t);

    for (int layer = 0; layer < NLAY; layer++) {
        s4w_conv<<<dim3(NH, NB / 4), 256, 0, stream>>>(u_t, Lmat, Wc, Vmat, pr_, pi_, Dp, layer);
        s4w_proj_mfma<<<dim3(NB, 8), 512, 0, stream>>>(
            u_t, hbf, wbf, out_b, ln_w, ln_b, layer < NLAY - 1 ? 1 : 0, layer);
    }

    s4w_mlp_wave<<<(NB * ML1 + 3) / 4, 256, 0, stream>>>(
        hbf + (size_t)(LSEQ - 1) * NH, (size_t)LSEQ * NH, lin1_w, lin1_b, t1, NH, ML1, 1, 1);
    s4w_mlp_wave<<<(NB * ML2 + 3) / 4, 256, 0, stream>>>(
        t1, ML1, lin2_w, lin2_b, t2, ML1, ML2, 1, 0);
    s4w_mlp_wave<<<(NB * MOUT + 3) / 4, 256, 0, stream>>>(
        t2, ML2, lin3_w, lin3_b, outp, ML2, MOUT, 0, 0);
}

// Round 16
// 298.326 us; speedup vs baseline: 1.6909x; 1.0861x over previous
//
#include <hip/hip_runtime.h>
#include <hip/hip_bf16.h>
#include <math.h>

#define NB 32
#define LSEQ 2048
#define DIN 64
#define NH 256
#define NN 32
#define NLAY 2
#define NCH 32
#define TCH 64    // LSEQ/NCH
#define NBC (NB*NCH)          // 1024 columns
#define LT 32                 // proj l-tile
#define ML1 350
#define ML2 400
#define MOUT 1024
#define LN_EPS 1e-5f

typedef short short8 __attribute__((ext_vector_type(8)));
typedef short short4v __attribute__((ext_vector_type(4)));
typedef float f32x4 __attribute__((ext_vector_type(4)));

__device__ __forceinline__ float bf2f(ushort u) {
    union { uint i; float f; } v; v.i = ((uint)u) << 16; return v.f;
}
__device__ __forceinline__ ushort f2bf(float f) {
    __hip_bfloat16 h = __float2bfloat16(f);
    return *reinterpret_cast<ushort*>(&h);
}

// ---------------- coefficient prep (E^64 for scan) ----------------
__global__ void s4w_coef(const float* __restrict__ log_dt,
                         const float* __restrict__ log_A_real, const float* __restrict__ A_imag,
                         float* __restrict__ pr_, float* __restrict__ pi_) {
    int idx = blockIdx.x * 256 + threadIdx.x;
    if (idx >= NLAY * NH * NN) return;
    int h = (idx / NN) % NH;
    int l = idx / (NN * NH);
    float dt = expf(log_dt[l * NH + h]);
    float ar = -expf(log_A_real[idx]);
    float ai = A_imag[idx];
    double dre = (double)(ar * dt), dim = (double)(ai * dt);
    double exT = exp(dre * (double)TCH);
    double ang = dim * (double)TCH;
    pr_[idx] = (float)(exT * cos(ang));
    pi_[idx] = (float)(exT * sin(ang));
}

// ---------------- matrix prep: Lmat (causal kernel), Wc (carry), Vmat (end-state) ----------------
__global__ void s4w_matprep(const float* __restrict__ log_dt,
                            const float* __restrict__ C_re, const float* __restrict__ C_im,
                            const float* __restrict__ log_A_real, const float* __restrict__ A_imag,
                            ushort* __restrict__ Lmat, ushort* __restrict__ Wc,
                            ushort* __restrict__ Vmat) {
    int lh = blockIdx.x;          // layer*NH + h
    int t = threadIdx.x;          // 0..63
    __shared__ float ksh[64];
    float dt = expf(log_dt[lh]);
    float kacc = 0.f;
    for (int n = 0; n < NN; n++) {
        int idx = lh * NN + n;
        float ar = -expf(log_A_real[idx]);
        float ai = A_imag[idx];
        float dre = ar * dt, dim = ai * dt;
        float e1 = expf(dre);
        float er1 = e1 * cosf(dim), ei1 = e1 * sinf(dim);
        float den = ar * ar + ai * ai;
        float qr = ((er1 - 1.f) * ar + ei1 * ai) / den;
        float qi = (ei1 * ar - (er1 - 1.f) * ai) / den;
        float cr = C_re[idx], ci = C_im[idx];
        float ctr = 2.f * (cr * qr - ci * qi);
        float cti = 2.f * (cr * qi + ci * qr);
        float ed = expf(dre * (float)t);
        float angd = dim * (float)t;
        float erd = ed * cosf(angd), eid = ed * sinf(angd);
        kacc += ctr * erd - cti * eid;
        float ew = expf(dre * (float)(t + 1));
        float angw = dim * (float)(t + 1);
        float ewr = ew * cosf(angw), ewi = ew * sinf(angw);
        float wr = ctr * ewr - cti * ewi;
        float wi = ctr * ewi + cti * ewr;
        Wc[(size_t)lh * 4096 + t * 64 + 2 * n]     = f2bf(wr);
        Wc[(size_t)lh * 4096 + t * 64 + 2 * n + 1] = f2bf(-wi);
        float ev = expf(dre * (float)(63 - t));
        float angv = dim * (float)(63 - t);
        Vmat[(size_t)lh * 4096 + (2 * n) * 64 + t]     = f2bf(ev * cosf(angv));
        Vmat[(size_t)lh * 4096 + (2 * n + 1) * 64 + t] = f2bf(ev * sinf(angv));
    }
    ksh[t] = kacc;
    __syncthreads();
    for (int j = 0; j < 64; j++)
        Lmat[(size_t)lh * 4096 + t * 64 + j] = (j <= t) ? f2bf(ksh[t - j]) : (ushort)0;
}

// ---------------- weight prep: f32 -> bf16 ----------------
__global__ void s4w_wprep(const float* __restrict__ src, ushort* __restrict__ dst, int n) {
    int idx = blockIdx.x * 256 + threadIdx.x;
    if (idx < n) dst[idx] = f2bf(src[idx]);
}

// ---------------- encoder (MFMA): block=(b,c 64-l chunk) -> r_t h-major ----------------
__global__ void __launch_bounds__(256, 2)
s4w_enc(const float* __restrict__ x, const ushort* __restrict__ wenc,
        const float* __restrict__ bias, ushort* __restrict__ r_t) {
    int b = blockIdx.x, c = blockIdx.y;
    int t = threadIdx.x;
    int wave = t >> 6, lane = t & 63;
    int lm = lane & 15, kg = lane >> 4;
    __shared__ __align__(16) ushort xsb[64][72];    // [l][i]
    __shared__ __align__(16) ushort ysb[256][72];   // [h][l]

    // stage x -> bf16 LDS
#pragma unroll
    for (int p = 0; p < 4; p++) {
        int cid = p * 256 + t;
        int l = cid >> 4, i4 = (cid & 15) * 4;
        float4 v = *(const float4*)(x + ((size_t)(b * LSEQ + c * 64 + l)) * DIN + i4);
        xsb[l][i4]     = f2bf(v.x); xsb[l][i4 + 1] = f2bf(v.y);
        xsb[l][i4 + 2] = f2bf(v.z); xsb[l][i4 + 3] = f2bf(v.w);
    }
    __syncthreads();

    f32x4 acc[4][4];
#pragma unroll
    for (int i = 0; i < 4; i++)
#pragma unroll
        for (int j = 0; j < 4; j++) acc[i][j] = (f32x4){0.f, 0.f, 0.f, 0.f};
#pragma unroll
    for (int ks = 0; ks < 2; ks++) {
        short8 av[4], bv[4];
#pragma unroll
        for (int mf = 0; mf < 4; mf++)
            av[mf] = *(const short8*)(wenc + (size_t)(wave * 64 + mf * 16 + lm) * DIN + ks * 32 + kg * 8);
#pragma unroll
        for (int nf = 0; nf < 4; nf++)
            bv[nf] = *(const short8*)&xsb[nf * 16 + lm][ks * 32 + kg * 8];
#pragma unroll
        for (int mf = 0; mf < 4; mf++)
#pragma unroll
            for (int nf = 0; nf < 4; nf++)
                acc[mf][nf] = __builtin_amdgcn_mfma_f32_16x16x32_bf16(av[mf], bv[nf], acc[mf][nf], 0, 0, 0);
    }
    float bb[4][4];
#pragma unroll
    for (int mf = 0; mf < 4; mf++)
#pragma unroll
        for (int j = 0; j < 4; j++)
            bb[mf][j] = bias[wave * 64 + mf * 16 + kg * 4 + j];
#pragma unroll
    for (int mf = 0; mf < 4; mf++)
#pragma unroll
        for (int nf = 0; nf < 4; nf++)
#pragma unroll
            for (int j = 0; j < 4; j++) {
                int h = wave * 64 + mf * 16 + kg * 4 + j;
                int l = nf * 16 + lm;
                ysb[h][l] = f2bf(acc[mf][nf][j] + bb[mf][j]);
            }
    __syncthreads();
    // write r_t: thread t = h, 128 B contiguous
    ushort* rd = r_t + ((size_t)t * NBC + b * NCH + c) * 64;
#pragma unroll
    for (int q = 0; q < 8; q++)
        *(short8*)(rd + q * 8) = *(const short8*)&ysb[t][q * 8];
}

// ---------------- fused conv: reads r_t, writes u_t; block = (h, 4 b's) ----------------
__global__ void __launch_bounds__(256, 3)
s4w_conv(const ushort* __restrict__ r_t, ushort* __restrict__ u_t,
         const ushort* __restrict__ Lmat, const ushort* __restrict__ Wc,
         const ushort* __restrict__ Vmat,
         const float* __restrict__ pr_, const float* __restrict__ pi_,
         const float* __restrict__ Dp, int layer) {
    int h = blockIdx.x, bq = blockIdx.y;
    int t = threadIdx.x;
    int wave = t >> 6, lane = t & 63;
    int lm = lane & 15, kg = lane >> 4;

    __shared__ __align__(16) ushort uS[NCH][72];
    __shared__ __align__(16) ushort lS[64][72];
    __shared__ __align__(16) ushort wS[64][72];
    __shared__ __align__(16) ushort vS[64][72];
    __shared__ __align__(16) float  stS[NCH][68];
    __shared__ __align__(16) ushort sbS[NCH][72];
    __shared__ __align__(16) ushort yS[NCH][72];

    const ushort* Lg = Lmat + (size_t)(layer * NH + h) * 4096;
    const ushort* Wg = Wc   + (size_t)(layer * NH + h) * 4096;
    const ushort* Vg = Vmat + (size_t)(layer * NH + h) * 4096;
#pragma unroll
    for (int p = 0; p < 2; p++) {
        int cid = p * 256 + t;
        int r = cid >> 3, o = (cid & 7) * 8;
        *(short8*)&lS[r][o] = *(const short8*)(Lg + r * 64 + o);
        *(short8*)&wS[r][o] = *(const short8*)(Wg + r * 64 + o);
        *(short8*)&vS[r][o] = *(const short8*)(Vg + r * 64 + o);
    }
    float dp = Dp[layer * NH + h];
    float prv = 0.f, piv = 0.f;
    if (t < NN) {
        prv = pr_[(size_t)(layer * NH + h) * NN + t];
        piv = pi_[(size_t)(layer * NH + h) * NN + t];
    }

    for (int bi = 0; bi < 4; bi++) {
        int b = bq * 4 + bi;
        const ushort* rb = r_t + ((size_t)h * NBC + b * NCH) * 64;
        ushort* ub = u_t + ((size_t)h * NBC + b * NCH) * 64;
        {
            int r = t >> 3, o = (t & 7) * 8;
            *(short8*)&uS[r][o] = *(const short8*)(rb + r * 64 + o);
        }
        __syncthreads();

        // phase 1: end states = Vmat @ u
        {
            f32x4 acc[2];
            acc[0] = (f32x4){0.f, 0.f, 0.f, 0.f};
            acc[1] = (f32x4){0.f, 0.f, 0.f, 0.f};
#pragma unroll
            for (int ks = 0; ks < 2; ks++) {
                short8 av = *(const short8*)&vS[wave * 16 + lm][ks * 32 + kg * 8];
#pragma unroll
                for (int nt = 0; nt < 2; nt++) {
                    short8 bv = *(const short8*)&uS[nt * 16 + lm][ks * 32 + kg * 8];
                    acc[nt] = __builtin_amdgcn_mfma_f32_16x16x32_bf16(av, bv, acc[nt], 0, 0, 0);
                }
            }
#pragma unroll
            for (int nt = 0; nt < 2; nt++) {
                int c = nt * 16 + lm;
                int comp = wave * 16 + kg * 4;
                *(f32x4*)&stS[c][comp] = acc[nt];
            }
        }
        __syncthreads();

        // phase 2: scan
        if (t < NN) {
            float sr = 0.f, si = 0.f;
            for (int c = 0; c < NCH; c++) {
                float er = stS[c][2 * t], ei = stS[c][2 * t + 1];
                sbS[c][2 * t] = f2bf(sr);
                sbS[c][2 * t + 1] = f2bf(si);
                float nsr = prv * sr - piv * si + er;
                float nsi = prv * si + piv * sr + ei;
                sr = nsr; si = nsi;
            }
        }
        __syncthreads();

        // phase 3: Y = Lmat @ u + Wc @ s_start
        f32x4 acc[2];
        acc[0] = (f32x4){0.f, 0.f, 0.f, 0.f};
        acc[1] = (f32x4){0.f, 0.f, 0.f, 0.f};
#pragma unroll
        for (int ks = 0; ks < 2; ks++) {
            short8 avL = *(const short8*)&lS[wave * 16 + lm][ks * 32 + kg * 8];
            short8 avW = *(const short8*)&wS[wave * 16 + lm][ks * 32 + kg * 8];
#pragma unroll
            for (int nt = 0; nt < 2; nt++) {
                short8 bvU = *(const short8*)&uS[nt * 16 + lm][ks * 32 + kg * 8];
                acc[nt] = __builtin_amdgcn_mfma_f32_16x16x32_bf16(avL, bvU, acc[nt], 0, 0, 0);
                short8 bvS = *(const short8*)&sbS[nt * 16 + lm][ks * 32 + kg * 8];
                acc[nt] = __builtin_amdgcn_mfma_f32_16x16x32_bf16(avW, bvS, acc[nt], 0, 0, 0);
            }
        }
        float dpv = dp;
#pragma unroll
        for (int nt = 0; nt < 2; nt++) {
            int c = nt * 16 + lm;
            int j0 = wave * 16 + kg * 4;
            short4v uv = *(const short4v*)&uS[c][j0];
            short4v yo;
#pragma unroll
            for (int jj = 0; jj < 4; jj++) {
                float u = bf2f((ushort)uv[jj]);
                float y = acc[nt][jj] + dpv * u;
                float g = 0.5f * y * (1.0f + erff(y * 0.70710678118f));
                yo[jj] = (short)f2bf(g);
            }
            *(short4v*)&yS[c][j0] = yo;
        }
        __syncthreads();
        {
            int r = t >> 3, o = (t & 7) * 8;
            *(short8*)(ub + r * 64 + o) = *(const short8*)&yS[r][o];
        }
        __syncthreads();
    }
}

// ---------------- proj v6: ys from u_t, residual from r_t, LN out -> r_t; hl gather ----------------
__global__ void __launch_bounds__(512, 2)
s4w_proj_mfma(const ushort* __restrict__ u_t, ushort* __restrict__ r_t,
              const ushort* __restrict__ wbf, const float* __restrict__ ob,
              const float* __restrict__ lnw, const float* __restrict__ lnb,
              float* __restrict__ hl, int last, int layer) {
    int b = blockIdx.x;
    int chunk = blockIdx.y;            // 8 chunks of 256 l
    int t = threadIdx.x;
    int wave = t >> 6, lane = t & 63;
    int lm = lane & 15, kg = lane >> 4;
    int hch = t & 255, lp = t >> 8;

    __shared__ __align__(16) char sbuf[LT * (NH + 1) * 4];   // ys/glu alias
    typedef ushort ysrow[NH + 8];
    typedef float glurow[NH + 1];
    ysrow* ys = (ysrow*)sbuf;
    glurow* glu = (glurow*)sbuf;
    __shared__ float ps[512], pq[512];
    __shared__ float mean_s[LT], rstd_s[LT];

    const ushort* wp = wbf + (size_t)layer * 512 * NH;

    short8 av[4][8];
#pragma unroll
    for (int mi = 0; mi < 4; mi++) {
        int o = (mi < 2 ? wave * 32 + mi * 16 : 256 + wave * 32 + (mi - 2) * 16) + lm;
#pragma unroll
        for (int ks = 0; ks < 8; ks++)
            av[mi][ks] = *(const short8*)(wp + (size_t)o * NH + ks * 32 + kg * 8);
    }

    float oba[2][4], obg[2][4];
#pragma unroll
    for (int mi = 0; mi < 2; mi++)
#pragma unroll
        for (int j = 0; j < 4; j++) {
            int o = wave * 32 + mi * 16 + kg * 4 + j;
            oba[mi][j] = ob[layer * 2 * NH + o];
            obg[mi][j] = ob[layer * 2 * NH + NH + o];
        }
    float lw = lnw[layer * NH + hch], lb = lnb[layer * NH + hch];

    // prefetch tile 0: ys (u_t) and residual (r_t)
    short8 pre0, pre1, rpre0, rpre1;
    {
        int l0 = chunk * 256;
        int c = l0 >> 6, j0 = l0 & 63;
        size_t base = ((size_t)hch * NBC + b * NCH + c) * 64 + j0 + lp * 16;
        pre0 = *(const short8*)(u_t + base);
        pre1 = *(const short8*)(u_t + base + 8);
        rpre0 = *(const short8*)(r_t + base);
        rpre1 = *(const short8*)(r_t + base + 8);
    }

    for (int tile = 0; tile < 8; tile++) {
        int l0 = chunk * 256 + tile * LT;
        int c = l0 >> 6, j0 = l0 & 63;
        size_t tbase = ((size_t)hch * NBC + b * NCH + c) * 64 + j0 + lp * 16;

        // write prefetched ys regs -> LDS transpose
        {
            int li0 = lp * 16;
#pragma unroll
            for (int i = 0; i < 8; i++) ys[li0 + i][hch] = (ushort)pre0[i];
#pragma unroll
            for (int i = 0; i < 8; i++) ys[li0 + 8 + i][hch] = (ushort)pre1[i];
        }
        short8 res0 = rpre0, res1 = rpre1;
        // prefetch next tile
        if (tile < 7) {
            int l0n = l0 + LT;
            int cn = l0n >> 6, j0n = l0n & 63;
            size_t nbase = ((size_t)hch * NBC + b * NCH + cn) * 64 + j0n + lp * 16;
            pre0 = *(const short8*)(u_t + nbase);
            pre1 = *(const short8*)(u_t + nbase + 8);
            rpre0 = *(const short8*)(r_t + nbase);
            rpre1 = *(const short8*)(r_t + nbase + 8);
        }
        __syncthreads();

        f32x4 acc[4][2];
#pragma unroll
        for (int i = 0; i < 4; i++)
#pragma unroll
            for (int j = 0; j < 2; j++) acc[i][j] = (f32x4){0.f, 0.f, 0.f, 0.f};

#pragma unroll
        for (int ks = 0; ks < 8; ks++) {
            short8 bv[2];
#pragma unroll
            for (int ni = 0; ni < 2; ni++)
                bv[ni] = *(const short8*)&ys[ni * 16 + lm][ks * 32 + kg * 8];
#pragma unroll
            for (int mi = 0; mi < 4; mi++)
#pragma unroll
                for (int ni = 0; ni < 2; ni++)
                    acc[mi][ni] = __builtin_amdgcn_mfma_f32_16x16x32_bf16(av[mi][ks], bv[ni], acc[mi][ni], 0, 0, 0);
        }
        __syncthreads();   // ys reads done before glu overwrite

        // bias + GLU -> glu
#pragma unroll
        for (int mi = 0; mi < 2; mi++)
#pragma unroll
            for (int ni = 0; ni < 2; ni++)
#pragma unroll
                for (int j = 0; j < 4; j++) {
                    float a = acc[mi][ni][j] + oba[mi][j];
                    float g = acc[mi + 2][ni][j] + obg[mi][j];
                    float v = a * (1.0f / (1.0f + expf(-g)));
                    glu[ni * 16 + lm][wave * 32 + mi * 16 + kg * 4 + j] = v;
                }
        __syncthreads();

        // residual add from regs
#pragma unroll
        for (int lq = 0; lq < 8; lq++)
            glu[lp * 16 + lq][hch] += bf2f((ushort)res0[lq]);
#pragma unroll
        for (int lq = 0; lq < 8; lq++)
            glu[lp * 16 + 8 + lq][hch] += bf2f((ushort)res1[lq]);
        __syncthreads();

        // LN stats
        {
            int l = t & 31, seg = t >> 5;
            float s = 0.f, q = 0.f;
#pragma unroll
            for (int i = 0; i < 16; i++) {
                float v = glu[l][seg * 16 + i];
                s += v; q = fmaf(v, v, q);
            }
            ps[t] = s; pq[t] = q;
        }
        __syncthreads();
        if (t < LT) {
            float S = 0.f, Q = 0.f;
#pragma unroll
            for (int k = 0; k < 16; k++) { S += ps[k * 32 + t]; Q += pq[k * 32 + t]; }
            float m = S * (1.0f / NH);
            float v = Q * (1.0f / NH) - m * m;
            mean_s[t] = m; rstd_s[t] = rsqrtf(v + LN_EPS);
        }
        __syncthreads();

        short8 o0, o1;
#pragma unroll
        for (int lq = 0; lq < 8; lq++) {
            int l = lp * 16 + lq;
            float v = (glu[l][hch] - mean_s[l]) * rstd_s[l] * lw + lb;
            o0[lq] = (short)f2bf(v);
        }
#pragma unroll
        for (int lq = 0; lq < 8; lq++) {
            int l = lp * 16 + 8 + lq;
            float v = (glu[l][hch] - mean_s[l]) * rstd_s[l] * lw + lb;
            o1[lq] = (short)f2bf(v);
            if (last && chunk == 7 && tile == 7 && lp == 1 && lq == 7)
                hl[(size_t)b * NH + hch] = v;   // l = 2047
        }
        ushort* rd = r_t + tbase;
        *(short8*)rd = o0;
        *(short8*)(rd + 8) = o1;
        __syncthreads();   // glu reads done before next tile's ys write
    }
}

// ---------------- head MLP: one wave per output element ----------------
__global__ void __launch_bounds__(256, 4)
s4w_mlp_wave(const float* __restrict__ in, size_t in_bstride,
             const float* __restrict__ w, const float* __restrict__ bias,
             float* __restrict__ out, int K, int N, int do_relu) {
    int wid = (blockIdx.x * 256 + threadIdx.x) >> 6;
    int lane = threadIdx.x & 63;
    if (wid >= NB * N) return;
    int b = wid / N, o = wid % N;
    const float* ip = in + (size_t)b * in_bstride;
    const float* wp = w + (size_t)o * K;
    float acc = 0.f;
    for (int k = lane; k < K; k += 64) acc = fmaf(wp[k], ip[k], acc);
#pragma unroll
    for (int off = 32; off > 0; off >>= 1) acc += __shfl_xor(acc, off, 64);
    if (lane == 0) {
        float v = acc + bias[o];
        out[(size_t)b * N + o] = do_relu ? fmaxf(v, 0.f) : v;
    }
}

extern "C" void kernel_launch(void* const* d_in, const int* in_sizes, int n_in,
                              void* d_out, int out_size, void* d_ws, size_t ws_size,
                              hipStream_t stream) {
    const float* x          = (const float*)d_in[0];
    const float* enc_w      = (const float*)d_in[1];
    const float* enc_b      = (const float*)d_in[2];
    const float* log_dt     = (const float*)d_in[3];
    const float* C_re       = (const float*)d_in[4];
    const float* C_im       = (const float*)d_in[5];
    const float* log_A_real = (const float*)d_in[6];
    const float* A_imag     = (const float*)d_in[7];
    const float* Dp         = (const float*)d_in[8];
    const float* out_w      = (const float*)d_in[9];
    const float* out_b      = (const float*)d_in[10];
    const float* ln_w       = (const float*)d_in[11];
    const float* ln_b       = (const float*)d_in[12];
    const float* lin1_w     = (const float*)d_in[13];
    const float* lin1_b     = (const float*)d_in[14];
    const float* lin2_w     = (const float*)d_in[15];
    const float* lin2_b     = (const float*)d_in[16];
    const float* lin3_w     = (const float*)d_in[17];
    const float* lin3_b     = (const float*)d_in[18];
    float* outp = (float*)d_out;

    float* ws = (float*)d_ws;
    size_t off = 0;
    ushort* r_t = (ushort*)(ws + off);   off += (size_t)NB * LSEQ * NH / 2;
    ushort* u_t = (ushort*)(ws + off);   off += (size_t)NB * LSEQ * NH / 2;
    ushort* wbf = (ushort*)(ws + off);   off += (size_t)NLAY * 2 * NH * NH / 2;
    ushort* wenc = (ushort*)(ws + off);  off += (size_t)NH * DIN / 2;
    ushort* Lmat = (ushort*)(ws + off);  off += (size_t)NLAY * NH * 4096 / 2;
    ushort* Wc   = (ushort*)(ws + off);  off += (size_t)NLAY * NH * 4096 / 2;
    ushort* Vmat = (ushort*)(ws + off);  off += (size_t)NLAY * NH * 4096 / 2;
    float* pr_ = ws + off;               off += NLAY * NH * NN;
    float* pi_ = ws + off;               off += NLAY * NH * NN;
    float* hl  = ws + off;               off += NB * NH;
    float* t1  = ws + off;               off += NB * ML1;
    float* t2  = ws + off;               off += NB * ML2;

    s4w_coef<<<(NLAY * NH * NN + 255) / 256, 256, 0, stream>>>(
        log_dt, log_A_real, A_imag, pr_, pi_);
    s4w_matprep<<<NLAY * NH, 64, 0, stream>>>(
        log_dt, C_re, C_im, log_A_real, A_imag, Lmat, Wc, Vmat);
    s4w_wprep<<<(NLAY * 2 * NH * NH + 255) / 256, 256, 0, stream>>>(out_w, wbf, NLAY * 2 * NH * NH);
    s4w_wprep<<<(NH * DIN + 255) / 256, 256, 0, stream>>>(enc_w, wenc, NH * DIN);

    s4w_enc<<<dim3(NB, 32), 256, 0, stream>>>(x, wenc, enc_b, r_t);

    for (int layer = 0; layer < NLAY; layer++) {
        s4w_conv<<<dim3(NH, NB / 4), 256, 0, stream>>>(r_t, u_t, Lmat, Wc, Vmat, pr_, pi_, Dp, layer);
        s4w_proj_mfma<<<dim3(NB, 8), 512, 0, stream>>>(
            u_t, r_t, wbf, out_b, ln_w, ln_b, hl, layer == NLAY - 1 ? 1 : 0, layer);
    }

    s4w_mlp_wave<<<(NB * ML1 + 3) / 4, 256, 0, stream>>>(
        hl, NH, lin1_w, lin1_b, t1, NH, ML1, 1);
    s4w_mlp_wave<<<(NB * ML2 + 3) / 4, 256, 0, stream>>>(
        t1, ML1, lin2_w, lin2_b, t2, ML1, ML2, 1);
    s4w_mlp_wave<<<(NB * MOUT + 3) / 4, 256, 0, stream>>>(
        t2, ML2, lin3_w, lin3_b, outp, ML2, MOUT, 0);
}